// Round 1
// baseline (8475.869 us; speedup 1.0000x reference)
//
#include <hip/hip_runtime.h>
#include <math.h>

#define EPSV 1e-5f

// ---------------- prep: w_reg (Co=256, C=256, 3,3) -> wT2[k][c][o] ----------------
__global__ void prep_wT2(const float* __restrict__ w_reg, float* __restrict__ wT2) {
    int e = blockIdx.x * 256 + threadIdx.x;      // e = (k*256 + c)*256 + o, N = 589824
    int o = e & 255;
    int t = e >> 8;
    int c = t & 255;
    int k = t >> 8;
    wT2[e] = w_reg[(o * 256 + c) * 9 + k];
}

// ---------------- prep: w_up (Cin=256, Cout=256, 4,4) -> wTup[c][ky][kx][o] -------
__global__ void prep_wTup(const float* __restrict__ w_up, float* __restrict__ wTup) {
    int e = blockIdx.x * 256 + threadIdx.x;      // e = ((c*4+ky)*4+kx)*256 + o, N = 1048576
    int o = e & 255;
    int t = e >> 8;       // c*16 + ky*4 + kx
    int kk = t & 15;
    int c = t >> 4;
    wTup[e] = w_up[(c * 256 + o) * 16 + kk];
}

// ---------------- k1: offset(18ch) + mask(9ch) 3x3 conv, 8-way c-split ------------
// grid = 8b * 16hg * 8split = 1024 blocks, 256 threads (4 rows x 64 w)
__global__ __launch_bounds__(256) void k1_offmask(
    const float* __restrict__ x, const float* __restrict__ w_off,
    const float* __restrict__ w_mod, float* __restrict__ part) {
    int bx = blockIdx.x;
    int s  = bx & 7;
    int hg = (bx >> 3) & 15;
    int b  = bx >> 7;
    int row = threadIdx.x >> 6;
    int w   = threadIdx.x & 63;
    int h   = hg * 4 + row;

    float acc[27];
#pragma unroll
    for (int i = 0; i < 27; ++i) acc[i] = 0.f;

    const float* xb = x + (size_t)b * 256 * 4096;
    int c0 = s * 32;
    for (int c = c0; c < c0 + 32; ++c) {
        float xv[9];
#pragma unroll
        for (int dy = 0; dy < 3; ++dy) {
            int yy = h - 1 + dy;
#pragma unroll
            for (int dx = 0; dx < 3; ++dx) {
                int xx = w - 1 + dx;
                bool ok = (yy >= 0) & (yy < 64) & (xx >= 0) & (xx < 64);
                xv[dy * 3 + dx] = ok ? xb[c * 4096 + yy * 64 + xx] : 0.f;
            }
        }
#pragma unroll
        for (int co = 0; co < 27; ++co) {
            const float* wp = (co < 18) ? (w_off + (co * 256 + c) * 9)
                                        : (w_mod + ((co - 18) * 256 + c) * 9);
            float a = acc[co];
#pragma unroll
            for (int t = 0; t < 9; ++t) a = fmaf(xv[t], wp[t], a);
            acc[co] = a;
        }
    }
    size_t base = (size_t)(s * 8 + b) * 27 * 4096 + h * 64 + w;
#pragma unroll
    for (int co = 0; co < 27; ++co) part[base + (size_t)co * 4096] = acc[co];
}

// ---------------- k1b: combine 8 partials + bias (+ 2*sigmoid for mask) ----------
// N = 8*27*4096 = 884736, grid 3456 x 256. offmask[(b*27+co)*4096 + hw]
__global__ void k1_combine(const float* __restrict__ part,
                           const float* __restrict__ b_off,
                           const float* __restrict__ b_mod,
                           float* __restrict__ offmask) {
    int e = blockIdx.x * 256 + threadIdx.x;
    int hw = e & 4095;
    int t  = e >> 12;
    int co = t % 27;
    int b  = t / 27;
    float sum = 0.f;
#pragma unroll
    for (int s = 0; s < 8; ++s)
        sum += part[(size_t)((s * 8 + b) * 27 + co) * 4096 + hw];
    if (co < 18) {
        sum += b_off[co];
    } else {
        sum += b_mod[co - 18];
        sum = 2.f / (1.f + expf(-sum));
    }
    offmask[e] = sum;
}

// ---------------- k2: deformable sample + einsum GEMM + bn1 + relu ---------------
// grid = b(8) * h(64) * oc(2) = 1024 blocks, 256 threads.
// thread: p2 = tid&31 -> positions {p2, p2+32}; og = tid>>5 -> 16 o's.
// Block tile: 64 positions x 128 output channels; K = 2304 (9 taps x 256 c).
__global__ __launch_bounds__(256) void k2_deform(
    const float* __restrict__ x, const float* __restrict__ offmask,
    const float* __restrict__ wT2,
    const float* __restrict__ g1, const float* __restrict__ be1,
    const float* __restrict__ mu1, const float* __restrict__ va1,
    float* __restrict__ h1) {
    __shared__ float lds_s[16 * 64];    // sampled [c_local][pos]
    __shared__ float lds_w[16 * 128];   // weights [c_local][o_local]

    int bx = blockIdx.x;
    int oc = bx & 1;
    int h  = (bx >> 1) & 63;
    int b  = bx >> 7;
    int tid = threadIdx.x;
    int p2 = tid & 31;
    int og = tid >> 5;     // 0..7

    float acc0[16], acc1[16];
#pragma unroll
    for (int i = 0; i < 16; ++i) { acc0[i] = 0.f; acc1[i] = 0.f; }

    const float* omb = offmask + (size_t)b * 27 * 4096 + h * 64;
    const float* xbb = x + (size_t)b * 256 * 4096;

    for (int k = 0; k < 9; ++k) {
        int ky = k / 3, kx = k % 3;
        int idx0[4], idx1[4];
        float wt0[4], wt1[4];
#pragma unroll
        for (int pp = 0; pp < 2; ++pp) {
            int pos = p2 + pp * 32;
            float oy = omb[(2 * k) * 4096 + pos];
            float ox = omb[(2 * k + 1) * 4096 + pos];
            float m2 = omb[(18 + k) * 4096 + pos];
            float py = (float)(h - 1 + ky) + oy;
            float px = (float)(pos - 1 + kx) + ox;
            float y0f = floorf(py), x0f = floorf(px);
            float wy1 = py - y0f, wy0 = 1.f - wy1;
            float wx1 = px - x0f, wx0 = 1.f - wx1;
            int y0 = (int)y0f, xq = (int)x0f;
            int y1 = y0 + 1, x1 = xq + 1;
            bool vy0 = (y0 >= 0) & (y0 < 64), vy1 = (y1 >= 0) & (y1 < 64);
            bool vx0 = (xq >= 0) & (xq < 64), vx1 = (x1 >= 0) & (x1 < 64);
            int y0c = min(max(y0, 0), 63), y1c = min(max(y1, 0), 63);
            int x0c = min(max(xq, 0), 63), x1c = min(max(x1, 0), 63);
            int i0 = y0c * 64 + x0c, i1 = y0c * 64 + x1c;
            int i2 = y1c * 64 + x0c, i3 = y1c * 64 + x1c;
            float t0 = (vy0 && vx0) ? m2 * wy0 * wx0 : 0.f;
            float t1 = (vy0 && vx1) ? m2 * wy0 * wx1 : 0.f;
            float t2 = (vy1 && vx0) ? m2 * wy1 * wx0 : 0.f;
            float t3 = (vy1 && vx1) ? m2 * wy1 * wx1 : 0.f;
            if (pp == 0) { idx0[0]=i0; idx0[1]=i1; idx0[2]=i2; idx0[3]=i3;
                           wt0[0]=t0; wt0[1]=t1; wt0[2]=t2; wt0[3]=t3; }
            else         { idx1[0]=i0; idx1[1]=i1; idx1[2]=i2; idx1[3]=i3;
                           wt1[0]=t0; wt1[1]=t1; wt1[2]=t2; wt1[3]=t3; }
        }

        for (int cc = 0; cc < 256; cc += 16) {
            // gather phase: each thread samples 2 channels x its 2 positions
#pragma unroll
            for (int u = 0; u < 2; ++u) {
                int cl = og * 2 + u;
                const float* xb = xbb + (size_t)(cc + cl) * 4096;
                float s0 = wt0[0] * xb[idx0[0]] + wt0[1] * xb[idx0[1]]
                         + wt0[2] * xb[idx0[2]] + wt0[3] * xb[idx0[3]];
                float s1 = wt1[0] * xb[idx1[0]] + wt1[1] * xb[idx1[1]]
                         + wt1[2] * xb[idx1[2]] + wt1[3] * xb[idx1[3]];
                lds_s[cl * 64 + p2]      = s0;
                lds_s[cl * 64 + p2 + 32] = s1;
            }
            // weight staging: 16c x 128o = 2048 floats, 8 per thread
            {
                int cl2 = tid >> 4;           // 0..15
                int ol  = (tid & 15) * 8;
                const float* src = wT2 + (size_t)(k * 256 + cc + cl2) * 256 + oc * 128 + ol;
                float4 wv0 = ((const float4*)src)[0];
                float4 wv1 = ((const float4*)src)[1];
                ((float4*)&lds_w[cl2 * 128 + ol])[0] = wv0;
                ((float4*)&lds_w[cl2 * 128 + ol])[1] = wv1;
            }
            __syncthreads();
            // compute phase
#pragma unroll
            for (int cl = 0; cl < 16; ++cl) {
                float s0 = lds_s[cl * 64 + p2];
                float s1 = lds_s[cl * 64 + p2 + 32];
                const float4* wrow = (const float4*)&lds_w[cl * 128 + og * 16];
#pragma unroll
                for (int i4 = 0; i4 < 4; ++i4) {
                    float4 w4 = wrow[i4];
                    acc0[i4*4+0] = fmaf(s0, w4.x, acc0[i4*4+0]);
                    acc0[i4*4+1] = fmaf(s0, w4.y, acc0[i4*4+1]);
                    acc0[i4*4+2] = fmaf(s0, w4.z, acc0[i4*4+2]);
                    acc0[i4*4+3] = fmaf(s0, w4.w, acc0[i4*4+3]);
                    acc1[i4*4+0] = fmaf(s1, w4.x, acc1[i4*4+0]);
                    acc1[i4*4+1] = fmaf(s1, w4.y, acc1[i4*4+1]);
                    acc1[i4*4+2] = fmaf(s1, w4.z, acc1[i4*4+2]);
                    acc1[i4*4+3] = fmaf(s1, w4.w, acc1[i4*4+3]);
                }
            }
            __syncthreads();
        }
    }

    // epilogue: bn1 + relu, write h1[b][o][h][pos]
    int ob = oc * 128 + og * 16;
#pragma unroll
    for (int j = 0; j < 16; ++j) {
        int o = ob + j;
        float sc = g1[o] / sqrtf(va1[o] + EPSV);
        float sh = be1[o] - mu1[o] * sc;
        size_t outb = ((size_t)b * 256 + o) * 4096 + h * 64;
        h1[outb + p2]      = fmaxf(fmaf(acc0[j], sc, sh), 0.f);
        h1[outb + p2 + 32] = fmaxf(fmaf(acc1[j], sc, sh), 0.f);
    }
}

// ---------------- k3: conv_transpose 4x4 s2 p1 + bn2 + relu ----------------------
// Each output (y,x) = sum over c of exactly 4 taps (parity-determined).
// grid = b(8) * y(128) * xt(2) * oc(8) = 16384 blocks, 256 threads.
// thread: lane = tid&63 -> x = xt*64+lane; wave = tid>>6 -> 8 o's.
__global__ __launch_bounds__(256) void k3_convt(
    const float* __restrict__ h1, const float* __restrict__ wTup,
    const float* __restrict__ g2, const float* __restrict__ be2,
    const float* __restrict__ mu2, const float* __restrict__ va2,
    float* __restrict__ out) {
    int bx = blockIdx.x;
    int oc = bx & 7;
    int xt = (bx >> 3) & 1;
    int y  = (bx >> 4) & 127;
    int b  = bx >> 11;
    int lane = threadIdx.x & 63;
    int wv   = threadIdx.x >> 6;
    int xx = xt * 64 + lane;
    int ob = oc * 32 + wv * 8;

    int ky0 = (y + 1) & 1;
    int i_hi = (y + 1 - ky0) >> 1;
    int kx0 = (xx + 1) & 1;
    int j_hi = (xx + 1 - kx0) >> 1;
    bool r0 = i_hi < 64;
    bool r1 = i_hi >= 1;
    bool cA = j_hi < 64;
    bool cB = j_hi >= 1;

    float acc[8];
#pragma unroll
    for (int i = 0; i < 8; ++i) acc[i] = 0.f;

    const float* hb = h1 + (size_t)b * 256 * 4096;
    int offA = (ky0 * 4 + kx0) * 256 + ob;       // (ky0,   kx0)   -> tap a
    int offB = offA + 2 * 256;                    // (ky0,   kx0+2) -> tap bb
    int offC = offA + 8 * 256;                    // (ky0+2, kx0)   -> tap cv
    int offD = offA + 10 * 256;                   // (ky0+2, kx0+2) -> tap dv
    int ia = i_hi * 64 + j_hi;

#pragma unroll 2
    for (int c = 0; c < 256; ++c) {
        const float* hc = hb + (size_t)c * 4096;
        float a  = (r0 && cA) ? hc[ia]      : 0.f;
        float bb = (r0 && cB) ? hc[ia - 1]  : 0.f;
        float cv = (r1 && cA) ? hc[ia - 64] : 0.f;
        float dv = (r1 && cB) ? hc[ia - 65] : 0.f;
        const float* wc = wTup + (size_t)c * 4096;
        float4 wA0 = *(const float4*)(wc + offA);
        float4 wA1 = *(const float4*)(wc + offA + 4);
        float4 wB0 = *(const float4*)(wc + offB);
        float4 wB1 = *(const float4*)(wc + offB + 4);
        float4 wC0 = *(const float4*)(wc + offC);
        float4 wC1 = *(const float4*)(wc + offC + 4);
        float4 wD0 = *(const float4*)(wc + offD);
        float4 wD1 = *(const float4*)(wc + offD + 4);
        acc[0] += a * wA0.x + bb * wB0.x + cv * wC0.x + dv * wD0.x;
        acc[1] += a * wA0.y + bb * wB0.y + cv * wC0.y + dv * wD0.y;
        acc[2] += a * wA0.z + bb * wB0.z + cv * wC0.z + dv * wD0.z;
        acc[3] += a * wA0.w + bb * wB0.w + cv * wC0.w + dv * wD0.w;
        acc[4] += a * wA1.x + bb * wB1.x + cv * wC1.x + dv * wD1.x;
        acc[5] += a * wA1.y + bb * wB1.y + cv * wC1.y + dv * wD1.y;
        acc[6] += a * wA1.z + bb * wB1.z + cv * wC1.z + dv * wD1.z;
        acc[7] += a * wA1.w + bb * wB1.w + cv * wC1.w + dv * wD1.w;
    }

#pragma unroll
    for (int j = 0; j < 8; ++j) {
        int o = ob + j;
        float sc = g2[o] / sqrtf(va2[o] + EPSV);
        float sh = be2[o] - mu2[o] * sc;
        float v = fmaxf(fmaf(acc[j], sc, sh), 0.f);
        out[((size_t)(b * 256 + o) * 128 + y) * 128 + xx] = v;
    }
}

extern "C" void kernel_launch(void* const* d_in, const int* in_sizes, int n_in,
                              void* d_out, int out_size, void* d_ws, size_t ws_size,
                              hipStream_t stream) {
    const float* x      = (const float*)d_in[0];
    const float* w_off  = (const float*)d_in[1];
    const float* b_off  = (const float*)d_in[2];
    const float* w_mod  = (const float*)d_in[3];
    const float* b_mod  = (const float*)d_in[4];
    const float* w_reg  = (const float*)d_in[5];
    const float* g1     = (const float*)d_in[6];
    const float* be1    = (const float*)d_in[7];
    const float* mu1    = (const float*)d_in[8];
    const float* va1    = (const float*)d_in[9];
    const float* w_up   = (const float*)d_in[10];
    const float* g2     = (const float*)d_in[11];
    const float* be2    = (const float*)d_in[12];
    const float* mu2    = (const float*)d_in[13];
    const float* va2    = (const float*)d_in[14];

    float* ws      = (float*)d_ws;
    float* part    = ws;                      // 8*884736       = 7,077,888 floats
    float* offmask = part + 7077888;          // 884,736
    float* wT2     = offmask + 884736;        // 589,824
    float* wTup    = wT2 + 589824;            // 1,048,576
    float* h1      = wTup + 1048576;          // 8,388,608  (total ~72 MB)

    prep_wT2 <<<2304,  256, 0, stream>>>(w_reg, wT2);
    prep_wTup<<<4096,  256, 0, stream>>>(w_up, wTup);
    k1_offmask<<<1024, 256, 0, stream>>>(x, w_off, w_mod, part);
    k1_combine<<<3456, 256, 0, stream>>>(part, b_off, b_mod, offmask);
    k2_deform<<<1024,  256, 0, stream>>>(x, offmask, wT2, g1, be1, mu1, va1, h1);
    k3_convt <<<16384, 256, 0, stream>>>(h1, wTup, g2, be2, mu2, va2, (float*)d_out);
}

// Round 2
// 1726.484 us; speedup vs baseline: 4.9093x; 4.9093x over previous
//
#include <hip/hip_runtime.h>
#include <math.h>

#define EPSV 1e-5f

// ---------------- prep: w_reg (Co=256, C=256, 3,3) -> wT2[k][c][o] ----------------
__global__ void prep_wT2(const float* __restrict__ w_reg, float* __restrict__ wT2) {
    int e = blockIdx.x * 256 + threadIdx.x;      // e = (k*256 + c)*256 + o, N = 589824
    int o = e & 255;
    int t = e >> 8;
    int c = t & 255;
    int k = t >> 8;
    wT2[e] = w_reg[(o * 256 + c) * 9 + k];
}

// ---------------- prep: w_up (Cin=256, Cout=256, 4,4) -> wTup[c][ky][kx][o] -------
__global__ void prep_wTup(const float* __restrict__ w_up, float* __restrict__ wTup) {
    int e = blockIdx.x * 256 + threadIdx.x;      // e = ((c*4+ky)*4+kx)*256 + o, N = 1048576
    int o = e & 255;
    int t = e >> 8;       // c*16 + ky*4 + kx
    int kk = t & 15;
    int c = t >> 4;
    wTup[e] = w_up[(c * 256 + o) * 16 + kk];
}

// ---------------- k1: offset(18ch) + mask(9ch) 3x3 conv, 8-way c-split ------------
__global__ __launch_bounds__(256) void k1_offmask(
    const float* __restrict__ x, const float* __restrict__ w_off,
    const float* __restrict__ w_mod, float* __restrict__ part) {
    int bx = blockIdx.x;
    int s  = bx & 7;
    int hg = (bx >> 3) & 15;
    int b  = bx >> 7;
    int row = threadIdx.x >> 6;
    int w   = threadIdx.x & 63;
    int h   = hg * 4 + row;

    float acc[27];
#pragma unroll
    for (int i = 0; i < 27; ++i) acc[i] = 0.f;

    const float* xb = x + (size_t)b * 256 * 4096;
    int c0 = s * 32;
    for (int c = c0; c < c0 + 32; ++c) {
        float xv[9];
#pragma unroll
        for (int dy = 0; dy < 3; ++dy) {
            int yy = h - 1 + dy;
#pragma unroll
            for (int dx = 0; dx < 3; ++dx) {
                int xx = w - 1 + dx;
                bool ok = (yy >= 0) & (yy < 64) & (xx >= 0) & (xx < 64);
                xv[dy * 3 + dx] = ok ? xb[c * 4096 + yy * 64 + xx] : 0.f;
            }
        }
#pragma unroll
        for (int co = 0; co < 27; ++co) {
            const float* wp = (co < 18) ? (w_off + (co * 256 + c) * 9)
                                        : (w_mod + ((co - 18) * 256 + c) * 9);
            float a = acc[co];
#pragma unroll
            for (int t = 0; t < 9; ++t) a = fmaf(xv[t], wp[t], a);
            acc[co] = a;
        }
    }
    size_t base = (size_t)(s * 8 + b) * 27 * 4096 + h * 64 + w;
#pragma unroll
    for (int co = 0; co < 27; ++co) part[base + (size_t)co * 4096] = acc[co];
}

// ---------------- k1b: combine 8 partials + bias (+ 2*sigmoid for mask) ----------
__global__ void k1_combine(const float* __restrict__ part,
                           const float* __restrict__ b_off,
                           const float* __restrict__ b_mod,
                           float* __restrict__ offmask) {
    int e = blockIdx.x * 256 + threadIdx.x;
    int hw = e & 4095;
    int t  = e >> 12;
    int co = t % 27;
    int b  = t / 27;
    float sum = 0.f;
#pragma unroll
    for (int s = 0; s < 8; ++s)
        sum += part[(size_t)((s * 8 + b) * 27 + co) * 4096 + hw];
    if (co < 18) {
        sum += b_off[co];
    } else {
        sum += b_mod[co - 18];
        sum = 2.f / (1.f + expf(-sum));
    }
    offmask[e] = sum;
}

// ---------------- k2: deformable sample + einsum GEMM + bn1 + relu ---------------
__global__ __launch_bounds__(256) void k2_deform(
    const float* __restrict__ x, const float* __restrict__ offmask,
    const float* __restrict__ wT2,
    const float* __restrict__ g1, const float* __restrict__ be1,
    const float* __restrict__ mu1, const float* __restrict__ va1,
    float* __restrict__ h1) {
    __shared__ float lds_s[16 * 64];    // sampled [c_local][pos]
    __shared__ float lds_w[16 * 128];   // weights [c_local][o_local]

    int bx = blockIdx.x;
    int oc = bx & 1;
    int h  = (bx >> 1) & 63;
    int b  = bx >> 7;
    int tid = threadIdx.x;
    int p2 = tid & 31;
    int og = tid >> 5;     // 0..7

    float acc0[16], acc1[16];
#pragma unroll
    for (int i = 0; i < 16; ++i) { acc0[i] = 0.f; acc1[i] = 0.f; }

    const float* omb = offmask + (size_t)b * 27 * 4096 + h * 64;
    const float* xbb = x + (size_t)b * 256 * 4096;

    for (int k = 0; k < 9; ++k) {
        int ky = k / 3, kx = k % 3;
        int idx0[4], idx1[4];
        float wt0[4], wt1[4];
#pragma unroll
        for (int pp = 0; pp < 2; ++pp) {
            int pos = p2 + pp * 32;
            float oy = omb[(2 * k) * 4096 + pos];
            float ox = omb[(2 * k + 1) * 4096 + pos];
            float m2 = omb[(18 + k) * 4096 + pos];
            float py = (float)(h - 1 + ky) + oy;
            float px = (float)(pos - 1 + kx) + ox;
            float y0f = floorf(py), x0f = floorf(px);
            float wy1 = py - y0f, wy0 = 1.f - wy1;
            float wx1 = px - x0f, wx0 = 1.f - wx1;
            int y0 = (int)y0f, xq = (int)x0f;
            int y1 = y0 + 1, x1 = xq + 1;
            bool vy0 = (y0 >= 0) & (y0 < 64), vy1 = (y1 >= 0) & (y1 < 64);
            bool vx0 = (xq >= 0) & (xq < 64), vx1 = (x1 >= 0) & (x1 < 64);
            int y0c = min(max(y0, 0), 63), y1c = min(max(y1, 0), 63);
            int x0c = min(max(xq, 0), 63), x1c = min(max(x1, 0), 63);
            int i0 = y0c * 64 + x0c, i1 = y0c * 64 + x1c;
            int i2 = y1c * 64 + x0c, i3 = y1c * 64 + x1c;
            float t0 = (vy0 && vx0) ? m2 * wy0 * wx0 : 0.f;
            float t1 = (vy0 && vx1) ? m2 * wy0 * wx1 : 0.f;
            float t2 = (vy1 && vx0) ? m2 * wy1 * wx0 : 0.f;
            float t3 = (vy1 && vx1) ? m2 * wy1 * wx1 : 0.f;
            if (pp == 0) { idx0[0]=i0; idx0[1]=i1; idx0[2]=i2; idx0[3]=i3;
                           wt0[0]=t0; wt0[1]=t1; wt0[2]=t2; wt0[3]=t3; }
            else         { idx1[0]=i0; idx1[1]=i1; idx1[2]=i2; idx1[3]=i3;
                           wt1[0]=t0; wt1[1]=t1; wt1[2]=t2; wt1[3]=t3; }
        }

        for (int cc = 0; cc < 256; cc += 16) {
#pragma unroll
            for (int u = 0; u < 2; ++u) {
                int cl = og * 2 + u;
                const float* xb = xbb + (size_t)(cc + cl) * 4096;
                float s0 = wt0[0] * xb[idx0[0]] + wt0[1] * xb[idx0[1]]
                         + wt0[2] * xb[idx0[2]] + wt0[3] * xb[idx0[3]];
                float s1 = wt1[0] * xb[idx1[0]] + wt1[1] * xb[idx1[1]]
                         + wt1[2] * xb[idx1[2]] + wt1[3] * xb[idx1[3]];
                lds_s[cl * 64 + p2]      = s0;
                lds_s[cl * 64 + p2 + 32] = s1;
            }
            {
                int cl2 = tid >> 4;           // 0..15
                int ol  = (tid & 15) * 8;
                const float* src = wT2 + (size_t)(k * 256 + cc + cl2) * 256 + oc * 128 + ol;
                float4 wv0 = ((const float4*)src)[0];
                float4 wv1 = ((const float4*)src)[1];
                ((float4*)&lds_w[cl2 * 128 + ol])[0] = wv0;
                ((float4*)&lds_w[cl2 * 128 + ol])[1] = wv1;
            }
            __syncthreads();
#pragma unroll
            for (int cl = 0; cl < 16; ++cl) {
                float s0 = lds_s[cl * 64 + p2];
                float s1 = lds_s[cl * 64 + p2 + 32];
                const float4* wrow = (const float4*)&lds_w[cl * 128 + og * 16];
#pragma unroll
                for (int i4 = 0; i4 < 4; ++i4) {
                    float4 w4 = wrow[i4];
                    acc0[i4*4+0] = fmaf(s0, w4.x, acc0[i4*4+0]);
                    acc0[i4*4+1] = fmaf(s0, w4.y, acc0[i4*4+1]);
                    acc0[i4*4+2] = fmaf(s0, w4.z, acc0[i4*4+2]);
                    acc0[i4*4+3] = fmaf(s0, w4.w, acc0[i4*4+3]);
                    acc1[i4*4+0] = fmaf(s1, w4.x, acc1[i4*4+0]);
                    acc1[i4*4+1] = fmaf(s1, w4.y, acc1[i4*4+1]);
                    acc1[i4*4+2] = fmaf(s1, w4.z, acc1[i4*4+2]);
                    acc1[i4*4+3] = fmaf(s1, w4.w, acc1[i4*4+3]);
                }
            }
            __syncthreads();
        }
    }

    int ob = oc * 128 + og * 16;
#pragma unroll
    for (int j = 0; j < 16; ++j) {
        int o = ob + j;
        float sc = g1[o] / sqrtf(va1[o] + EPSV);
        float sh = be1[o] - mu1[o] * sc;
        size_t outb = ((size_t)b * 256 + o) * 4096 + h * 64;
        h1[outb + p2]      = fmaxf(fmaf(acc0[j], sc, sh), 0.f);
        h1[outb + p2 + 32] = fmaxf(fmaf(acc1[j], sc, sh), 0.f);
    }
}

// ---------------- k3: conv_transpose 4x4 s2 p1 + bn2 + relu (v2: scalar weights) --
// Lanes cover x of a SINGLE parity (x = 2*lane + sx) so kx0 is wave-uniform;
// o-group made uniform via readfirstlane -> weight loads become s_load through
// the scalar cache (zero vector-L1 traffic for weights). 16 o per thread so the
// 4 h1 loads per c amortize over 64 FMAs.
// grid = b(8) * y(128) * sx(2) * oc(4) = 8192 blocks, 256 threads.
__global__ __launch_bounds__(256) void k3_convt(
    const float* __restrict__ h1, const float* __restrict__ wTup,
    const float* __restrict__ g2, const float* __restrict__ be2,
    const float* __restrict__ mu2, const float* __restrict__ va2,
    float* __restrict__ out) {
    int bx = blockIdx.x;
    int oc = bx & 3;
    int sx = (bx >> 2) & 1;
    int y  = (bx >> 3) & 127;
    int b  = bx >> 10;
    int lane = threadIdx.x & 63;
    int wvu  = __builtin_amdgcn_readfirstlane(threadIdx.x >> 6);   // force wave-uniform
    int xx = 2 * lane + sx;
    int ob = oc * 64 + wvu * 16;

    int ky0 = (y + 1) & 1;          // block-uniform
    int i0  = (y + 1 - ky0) >> 1;   // top input row; bottom = i0-1
    int kx0 = (sx + 1) & 1;         // wave-uniform (single x-parity per block)
    int j0  = lane + sx;            // input col for the kx0 taps; kx0+2 taps use j0-1

    bool r0 = (i0 <= 63);
    bool r1 = (i0 >= 1);
    bool cA = (j0 <= 63);
    bool cB = (j0 >= 1);
    int i0c = min(i0, 63);
    int i1c = max(i0 - 1, 0);
    int jA  = min(j0, 63);
    int jB  = max(j0 - 1, 0);

    float acc[16];
#pragma unroll
    for (int i = 0; i < 16; ++i) acc[i] = 0.f;

    const float* hb = h1 + (size_t)b * 256 * 4096;
    // wave-uniform weight offsets (same tap mapping as round-0 kernel)
    int off00 = (ky0 * 4 + kx0) * 256 + ob;   // tap (ky0,   kx0)   -> aT (row i0,   col j0)
    int off02 = off00 + 2 * 256;              // tap (ky0,   kx0+2) -> bT (row i0,   col j0-1)
    int off20 = off00 + 8 * 256;              // tap (ky0+2, kx0)   -> aB (row i0-1, col j0)
    int off22 = off00 + 10 * 256;             // tap (ky0+2, kx0+2) -> bB (row i0-1, col j0-1)

    int iTA = i0c * 64 + jA;
    int iTB = i0c * 64 + jB;
    int iBA = i1c * 64 + jA;
    int iBB = i1c * 64 + jB;

    for (int c = 0; c < 256; ++c) {
        const float* hc = hb + (size_t)c * 4096;
        float vTA = hc[iTA];
        float vTB = hc[iTB];
        float vBA = hc[iBA];
        float vBB = hc[iBB];
        float aT = (r0 && cA) ? vTA : 0.f;
        float bT = (r0 && cB) ? vTB : 0.f;
        float aB = (r1 && cA) ? vBA : 0.f;
        float bB = (r1 && cB) ? vBB : 0.f;

        const float* wc  = wTup + (size_t)c * 4096;
        const float* w00 = wc + off00;
        const float* w02 = wc + off02;
        const float* w20 = wc + off20;
        const float* w22 = wc + off22;
#pragma unroll
        for (int j = 0; j < 16; ++j) {
            float a = acc[j];
            a = fmaf(aT, w00[j], a);
            a = fmaf(bT, w02[j], a);
            a = fmaf(aB, w20[j], a);
            a = fmaf(bB, w22[j], a);
            acc[j] = a;
        }
    }

#pragma unroll
    for (int j = 0; j < 16; ++j) {
        int o = ob + j;
        float sc = g2[o] / sqrtf(va2[o] + EPSV);
        float sh = be2[o] - mu2[o] * sc;
        float v = fmaxf(fmaf(acc[j], sc, sh), 0.f);
        out[((size_t)(b * 256 + o) * 128 + y) * 128 + xx] = v;
    }
}

extern "C" void kernel_launch(void* const* d_in, const int* in_sizes, int n_in,
                              void* d_out, int out_size, void* d_ws, size_t ws_size,
                              hipStream_t stream) {
    const float* x      = (const float*)d_in[0];
    const float* w_off  = (const float*)d_in[1];
    const float* b_off  = (const float*)d_in[2];
    const float* w_mod  = (const float*)d_in[3];
    const float* b_mod  = (const float*)d_in[4];
    const float* w_reg  = (const float*)d_in[5];
    const float* g1     = (const float*)d_in[6];
    const float* be1    = (const float*)d_in[7];
    const float* mu1    = (const float*)d_in[8];
    const float* va1    = (const float*)d_in[9];
    const float* w_up   = (const float*)d_in[10];
    const float* g2     = (const float*)d_in[11];
    const float* be2    = (const float*)d_in[12];
    const float* mu2    = (const float*)d_in[13];
    const float* va2    = (const float*)d_in[14];

    float* ws      = (float*)d_ws;
    float* part    = ws;                      // 8*884736       = 7,077,888 floats
    float* offmask = part + 7077888;          // 884,736
    float* wT2     = offmask + 884736;        // 589,824
    float* wTup    = wT2 + 589824;            // 1,048,576
    float* h1      = wTup + 1048576;          // 8,388,608  (total ~72 MB)

    prep_wT2 <<<2304,  256, 0, stream>>>(w_reg, wT2);
    prep_wTup<<<4096,  256, 0, stream>>>(w_up, wTup);
    k1_offmask<<<1024, 256, 0, stream>>>(x, w_off, w_mod, part);
    k1_combine<<<3456, 256, 0, stream>>>(part, b_off, b_mod, offmask);
    k2_deform<<<1024,  256, 0, stream>>>(x, offmask, wT2, g1, be1, mu1, va1, h1);
    k3_convt <<<8192,  256, 0, stream>>>(h1, wTup, g2, be2, mu2, va2, (float*)d_out);
}

// Round 3
// 1088.302 us; speedup vs baseline: 7.7882x; 1.5864x over previous
//
#include <hip/hip_runtime.h>
#include <math.h>

#define EPSV 1e-5f

typedef __attribute__((ext_vector_type(8)))  short short8_t;
typedef __attribute__((ext_vector_type(16))) float f32x16;

static __device__ __forceinline__ short f2bf(float f) {
    union { float f; unsigned u; } v; v.f = f;
    unsigned r = (v.u + 0x7FFFu + ((v.u >> 16) & 1u)) >> 16;
    return (short)r;
}

// ---------------- prep: w_reg (Co=256, C=256, 3,3) -> wT2[k][c][o] ----------------
__global__ void prep_wT2(const float* __restrict__ w_reg, float* __restrict__ wT2) {
    int e = blockIdx.x * 256 + threadIdx.x;      // e = (k*256 + c)*256 + o, N = 589824
    int o = e & 255;
    int t = e >> 8;
    int c = t & 255;
    int k = t >> 8;
    wT2[e] = w_reg[(o * 256 + c) * 9 + k];
}

// ---------------- prep: w_up -> Bpack, MFMA-B-fragment order, bf16 ----------------
// Bpack[sy][sx][kstep s(64)][tile t(8)][lane l(64)][j(8)], element:
//   k = (l>>5)*8 + j; kk = s*16+k; c = kk>>2; tq = kk&3; ty=tq>>1; tx=tq&1;
//   ky = (1-sy)+2*ty; kx = (1-sx)+2*tx; o = t*32 + (l&31);
//   val = w_up[(c*256+o)*16 + ky*4 + kx]
__global__ void prep_Bpack(const float* __restrict__ w_up, short* __restrict__ Bpack) {
    int gid = blockIdx.x * 256 + threadIdx.x;    // 131072 threads, 8 elems each
    int l  = gid & 63;
    int t  = (gid >> 6) & 7;
    int s  = (gid >> 9) & 63;
    int sx = (gid >> 15) & 1;
    int sy = (gid >> 16) & 1;
    int o  = t * 32 + (l & 31);
    short v8[8];
#pragma unroll
    for (int j = 0; j < 8; ++j) {
        int k  = (l >> 5) * 8 + j;
        int kk = s * 16 + k;
        int c  = kk >> 2;
        int tq = kk & 3;
        int ky = (1 - sy) + 2 * (tq >> 1);
        int kx = (1 - sx) + 2 * (tq & 1);
        v8[j] = f2bf(w_up[(c * 256 + o) * 16 + ky * 4 + kx]);
    }
    short* dst = Bpack + (size_t)gid * 8;
#pragma unroll
    for (int j = 0; j < 8; ++j) dst[j] = v8[j];
}

// ---------------- k1: offset(18ch) + mask(9ch) 3x3 conv, 8-way c-split ------------
__global__ __launch_bounds__(256) void k1_offmask(
    const float* __restrict__ x, const float* __restrict__ w_off,
    const float* __restrict__ w_mod, float* __restrict__ part) {
    int bx = blockIdx.x;
    int s  = bx & 7;
    int hg = (bx >> 3) & 15;
    int b  = bx >> 7;
    int row = threadIdx.x >> 6;
    int w   = threadIdx.x & 63;
    int h   = hg * 4 + row;

    float acc[27];
#pragma unroll
    for (int i = 0; i < 27; ++i) acc[i] = 0.f;

    const float* xb = x + (size_t)b * 256 * 4096;
    int c0 = s * 32;
    for (int c = c0; c < c0 + 32; ++c) {
        float xv[9];
#pragma unroll
        for (int dy = 0; dy < 3; ++dy) {
            int yy = h - 1 + dy;
#pragma unroll
            for (int dx = 0; dx < 3; ++dx) {
                int xx = w - 1 + dx;
                bool ok = (yy >= 0) & (yy < 64) & (xx >= 0) & (xx < 64);
                xv[dy * 3 + dx] = ok ? xb[c * 4096 + yy * 64 + xx] : 0.f;
            }
        }
#pragma unroll
        for (int co = 0; co < 27; ++co) {
            const float* wp = (co < 18) ? (w_off + (co * 256 + c) * 9)
                                        : (w_mod + ((co - 18) * 256 + c) * 9);
            float a = acc[co];
#pragma unroll
            for (int t = 0; t < 9; ++t) a = fmaf(xv[t], wp[t], a);
            acc[co] = a;
        }
    }
    size_t base = (size_t)(s * 8 + b) * 27 * 4096 + h * 64 + w;
#pragma unroll
    for (int co = 0; co < 27; ++co) part[base + (size_t)co * 4096] = acc[co];
}

// ---------------- k1b: combine 8 partials + bias (+ 2*sigmoid for mask) ----------
__global__ void k1_combine(const float* __restrict__ part,
                           const float* __restrict__ b_off,
                           const float* __restrict__ b_mod,
                           float* __restrict__ offmask) {
    int e = blockIdx.x * 256 + threadIdx.x;
    int hw = e & 4095;
    int t  = e >> 12;
    int co = t % 27;
    int b  = t / 27;
    float sum = 0.f;
#pragma unroll
    for (int s = 0; s < 8; ++s)
        sum += part[(size_t)((s * 8 + b) * 27 + co) * 4096 + hw];
    if (co < 18) {
        sum += b_off[co];
    } else {
        sum += b_mod[co - 18];
        sum = 2.f / (1.f + expf(-sum));
    }
    offmask[e] = sum;
}

// ---------------- k2: deformable sample + einsum GEMM + bn1 + relu ---------------
__global__ __launch_bounds__(256) void k2_deform(
    const float* __restrict__ x, const float* __restrict__ offmask,
    const float* __restrict__ wT2,
    const float* __restrict__ g1, const float* __restrict__ be1,
    const float* __restrict__ mu1, const float* __restrict__ va1,
    float* __restrict__ h1) {
    __shared__ float lds_s[16 * 64];    // sampled [c_local][pos]
    __shared__ float lds_w[16 * 128];   // weights [c_local][o_local]

    int bx = blockIdx.x;
    int oc = bx & 1;
    int h  = (bx >> 1) & 63;
    int b  = bx >> 7;
    int tid = threadIdx.x;
    int p2 = tid & 31;
    int og = tid >> 5;     // 0..7

    float acc0[16], acc1[16];
#pragma unroll
    for (int i = 0; i < 16; ++i) { acc0[i] = 0.f; acc1[i] = 0.f; }

    const float* omb = offmask + (size_t)b * 27 * 4096 + h * 64;
    const float* xbb = x + (size_t)b * 256 * 4096;

    for (int k = 0; k < 9; ++k) {
        int ky = k / 3, kx = k % 3;
        int idx0[4], idx1[4];
        float wt0[4], wt1[4];
#pragma unroll
        for (int pp = 0; pp < 2; ++pp) {
            int pos = p2 + pp * 32;
            float oy = omb[(2 * k) * 4096 + pos];
            float ox = omb[(2 * k + 1) * 4096 + pos];
            float m2 = omb[(18 + k) * 4096 + pos];
            float py = (float)(h - 1 + ky) + oy;
            float px = (float)(pos - 1 + kx) + ox;
            float y0f = floorf(py), x0f = floorf(px);
            float wy1 = py - y0f, wy0 = 1.f - wy1;
            float wx1 = px - x0f, wx0 = 1.f - wx1;
            int y0 = (int)y0f, xq = (int)x0f;
            int y1 = y0 + 1, x1 = xq + 1;
            bool vy0 = (y0 >= 0) & (y0 < 64), vy1 = (y1 >= 0) & (y1 < 64);
            bool vx0 = (xq >= 0) & (xq < 64), vx1 = (x1 >= 0) & (x1 < 64);
            int y0c = min(max(y0, 0), 63), y1c = min(max(y1, 0), 63);
            int x0c = min(max(xq, 0), 63), x1c = min(max(x1, 0), 63);
            int i0 = y0c * 64 + x0c, i1 = y0c * 64 + x1c;
            int i2 = y1c * 64 + x0c, i3 = y1c * 64 + x1c;
            float t0 = (vy0 && vx0) ? m2 * wy0 * wx0 : 0.f;
            float t1 = (vy0 && vx1) ? m2 * wy0 * wx1 : 0.f;
            float t2 = (vy1 && vx0) ? m2 * wy1 * wx0 : 0.f;
            float t3 = (vy1 && vx1) ? m2 * wy1 * wx1 : 0.f;
            if (pp == 0) { idx0[0]=i0; idx0[1]=i1; idx0[2]=i2; idx0[3]=i3;
                           wt0[0]=t0; wt0[1]=t1; wt0[2]=t2; wt0[3]=t3; }
            else         { idx1[0]=i0; idx1[1]=i1; idx1[2]=i2; idx1[3]=i3;
                           wt1[0]=t0; wt1[1]=t1; wt1[2]=t2; wt1[3]=t3; }
        }

        for (int cc = 0; cc < 256; cc += 16) {
#pragma unroll
            for (int u = 0; u < 2; ++u) {
                int cl = og * 2 + u;
                const float* xb = xbb + (size_t)(cc + cl) * 4096;
                float s0 = wt0[0] * xb[idx0[0]] + wt0[1] * xb[idx0[1]]
                         + wt0[2] * xb[idx0[2]] + wt0[3] * xb[idx0[3]];
                float s1 = wt1[0] * xb[idx1[0]] + wt1[1] * xb[idx1[1]]
                         + wt1[2] * xb[idx1[2]] + wt1[3] * xb[idx1[3]];
                lds_s[cl * 64 + p2]      = s0;
                lds_s[cl * 64 + p2 + 32] = s1;
            }
            {
                int cl2 = tid >> 4;           // 0..15
                int ol  = (tid & 15) * 8;
                const float* src = wT2 + (size_t)(k * 256 + cc + cl2) * 256 + oc * 128 + ol;
                float4 wv0 = ((const float4*)src)[0];
                float4 wv1 = ((const float4*)src)[1];
                ((float4*)&lds_w[cl2 * 128 + ol])[0] = wv0;
                ((float4*)&lds_w[cl2 * 128 + ol])[1] = wv1;
            }
            __syncthreads();
#pragma unroll
            for (int cl = 0; cl < 16; ++cl) {
                float s0 = lds_s[cl * 64 + p2];
                float s1 = lds_s[cl * 64 + p2 + 32];
                const float4* wrow = (const float4*)&lds_w[cl * 128 + og * 16];
#pragma unroll
                for (int i4 = 0; i4 < 4; ++i4) {
                    float4 w4 = wrow[i4];
                    acc0[i4*4+0] = fmaf(s0, w4.x, acc0[i4*4+0]);
                    acc0[i4*4+1] = fmaf(s0, w4.y, acc0[i4*4+1]);
                    acc0[i4*4+2] = fmaf(s0, w4.z, acc0[i4*4+2]);
                    acc0[i4*4+3] = fmaf(s0, w4.w, acc0[i4*4+3]);
                    acc1[i4*4+0] = fmaf(s1, w4.x, acc1[i4*4+0]);
                    acc1[i4*4+1] = fmaf(s1, w4.y, acc1[i4*4+1]);
                    acc1[i4*4+2] = fmaf(s1, w4.z, acc1[i4*4+2]);
                    acc1[i4*4+3] = fmaf(s1, w4.w, acc1[i4*4+3]);
                }
            }
            __syncthreads();
        }
    }

    int ob = oc * 128 + og * 16;
#pragma unroll
    for (int j = 0; j < 16; ++j) {
        int o = ob + j;
        float sc = g1[o] / sqrtf(va1[o] + EPSV);
        float sh = be1[o] - mu1[o] * sc;
        size_t outb = ((size_t)b * 256 + o) * 4096 + h * 64;
        h1[outb + p2]      = fmaxf(fmaf(acc0[j], sc, sh), 0.f);
        h1[outb + p2 + 32] = fmaxf(fmaf(acc1[j], sc, sh), 0.f);
    }
}

// ---------------- k3: conv_transpose via bf16 MFMA (32x32x16) + bn2 + relu -------
// GEMM per block: M=64 (mx), N=256 (o), K=1024 (256 c x 4 taps), BOTH x-parities.
// Block = (sy, b, m): y = 2m+sy fixed. 4 waves: wave w -> M-half (w&1)*32,
// N-range (w>>1)*128 (4 tiles of 32). A staged in LDS (2 rows + halo, bf16),
// B read as prepacked fragments straight from global (L2-resident, 2 MB).
__global__ __launch_bounds__(256, 2) void k3_convt(
    const float* __restrict__ h1, const short* __restrict__ Bpack,
    const float* __restrict__ g2, const float* __restrict__ be2,
    const float* __restrict__ mu2, const float* __restrict__ va2,
    float* __restrict__ out) {
    __shared__ short halo[32 * 2 * 66];   // [c_local][row(top/bot)][col+1], bf16

    int bx = blockIdx.x;
    int m  = bx & 63;
    int b  = (bx >> 6) & 7;
    int sy = bx >> 9;
    int tid  = threadIdx.x;
    int lane = tid & 63;
    int w    = tid >> 6;
    int Mbase = (w & 1) * 32;
    int nb    = (w >> 1) * 4;     // first of 4 N-tiles (o = tile*32)
    int ln = lane & 31;
    int lh = lane >> 5;

    int i_top = sy ? (m + 1) : m;      // tap ty=0 input row
    int i_bot = sy ? m : (m - 1);      // tap ty=1 input row
    bool vtop = (i_top < 64);
    bool vbot = (i_bot >= 0);

    f32x16 acc[2][4];
#pragma unroll
    for (int s = 0; s < 2; ++s)
#pragma unroll
        for (int t = 0; t < 4; ++t)
#pragma unroll
            for (int r = 0; r < 16; ++r) acc[s][t][r] = 0.f;

    const float* hbase = h1 + (size_t)b * 256 * 4096;

    for (int cc = 0; cc < 256; cc += 32) {
        // ---- stage 32 c x 2 rows x 64 cols of h1 -> bf16 halo ----
#pragma unroll
        for (int it = 0; it < 16; ++it) {
            int e   = tid + it * 256;
            int c_l = e >> 7;
            int r   = (e >> 6) & 1;
            int col = e & 63;
            int i   = r ? i_bot : i_top;
            bool v  = r ? vbot : vtop;
            float f = v ? hbase[(size_t)(cc + c_l) * 4096 + i * 64 + col] : 0.f;
            halo[(c_l * 2 + r) * 66 + col + 1] = f2bf(f);
        }
        if (tid < 128) {
            int c_l = tid >> 2;
            int r   = (tid >> 1) & 1;
            int end = tid & 1;
            halo[(c_l * 2 + r) * 66 + end * 65] = 0;
        }
        __syncthreads();

#pragma unroll
        for (int s8 = 0; s8 < 8; ++s8) {
            int c0 = s8 * 4;
            // A fragments for both x-parities: a[sx][j], j -> (c_local, ty, tx)
            short8_t afr[2];
#pragma unroll
            for (int sx = 0; sx < 2; ++sx) {
#pragma unroll
                for (int j = 0; j < 8; ++j) {
                    int c_l = c0 + lh * 2 + (j >> 2);
                    int ty  = (j >> 1) & 1;
                    int tx  = j & 1;
                    afr[sx][j] = halo[(c_l * 2 + ty) * 66 + (Mbase + ln) + sx + 1 - tx];
                }
            }
            int sstep = (cc >> 2) + s8;   // global K-step index
#pragma unroll
            for (int sx = 0; sx < 2; ++sx) {
                size_t base = ((((size_t)(sy * 2 + sx) * 64 + sstep) * 8) * 64 + lane) * 8;
#pragma unroll
                for (int tt = 0; tt < 4; ++tt) {
                    short8_t bfr = *(const short8_t*)(Bpack + base + (size_t)(nb + tt) * 512);
                    acc[sx][tt] = __builtin_amdgcn_mfma_f32_32x32x16_bf16(
                        afr[sx], bfr, acc[sx][tt], 0, 0, 0);
                }
            }
        }
        __syncthreads();
    }

    // ---- epilogue: bn2 + relu; C/D layout col=lane&31, row=(reg&3)+8*(reg>>2)+4*lh
    int y = 2 * m + sy;
#pragma unroll
    for (int tt = 0; tt < 4; ++tt) {
        int o = (nb + tt) * 32 + ln;
        float sc = g2[o] / sqrtf(va2[o] + EPSV);
        float sh = be2[o] - mu2[o] * sc;
        size_t ob = ((size_t)(b * 256 + o) * 128 + y) * 128;
#pragma unroll
        for (int sx = 0; sx < 2; ++sx) {
#pragma unroll
            for (int reg = 0; reg < 16; ++reg) {
                int row = (reg & 3) + 8 * (reg >> 2) + 4 * lh;
                int xx = 2 * (Mbase + row) + sx;
                out[ob + xx] = fmaxf(fmaf(acc[sx][tt][reg], sc, sh), 0.f);
            }
        }
    }
}

extern "C" void kernel_launch(void* const* d_in, const int* in_sizes, int n_in,
                              void* d_out, int out_size, void* d_ws, size_t ws_size,
                              hipStream_t stream) {
    const float* x      = (const float*)d_in[0];
    const float* w_off  = (const float*)d_in[1];
    const float* b_off  = (const float*)d_in[2];
    const float* w_mod  = (const float*)d_in[3];
    const float* b_mod  = (const float*)d_in[4];
    const float* w_reg  = (const float*)d_in[5];
    const float* g1     = (const float*)d_in[6];
    const float* be1    = (const float*)d_in[7];
    const float* mu1    = (const float*)d_in[8];
    const float* va1    = (const float*)d_in[9];
    const float* w_up   = (const float*)d_in[10];
    const float* g2     = (const float*)d_in[11];
    const float* be2    = (const float*)d_in[12];
    const float* mu2    = (const float*)d_in[13];
    const float* va2    = (const float*)d_in[14];

    float* ws      = (float*)d_ws;
    float* part    = ws;                      // 7,077,888 floats
    float* offmask = part + 7077888;          // 884,736
    float* wT2     = offmask + 884736;        // 589,824
    short* Bpack   = (short*)(wT2 + 589824);  // 1,048,576 bf16 (= 524,288 floats)
    float* h1      = wT2 + 589824 + 524288;   // 8,388,608

    prep_wT2  <<<2304,  256, 0, stream>>>(w_reg, wT2);
    prep_Bpack<<<512,   256, 0, stream>>>(w_up, Bpack);
    k1_offmask<<<1024,  256, 0, stream>>>(x, w_off, w_mod, part);
    k1_combine<<<3456,  256, 0, stream>>>(part, b_off, b_mod, offmask);
    k2_deform <<<1024,  256, 0, stream>>>(x, offmask, wT2, g1, be1, mu1, va1, h1);
    k3_convt  <<<1024,  256, 0, stream>>>(h1, Bpack, g2, be2, mu2, va2, (float*)d_out);
}

// Round 4
// 733.179 us; speedup vs baseline: 11.5604x; 1.4844x over previous
//
#include <hip/hip_runtime.h>
#include <math.h>

#define EPSV 1e-5f

typedef __attribute__((ext_vector_type(8)))  short short8_t;
typedef __attribute__((ext_vector_type(16))) float f32x16;

static __device__ __forceinline__ short f2bf(float f) {
    union { float f; unsigned u; } v; v.f = f;
    unsigned r = (v.u + 0x7FFFu + ((v.u >> 16) & 1u)) >> 16;
    return (short)r;
}
static __device__ __forceinline__ unsigned pack2bf(float a, float b) {
    return (unsigned)(unsigned short)f2bf(a) | ((unsigned)(unsigned short)f2bf(b) << 16);
}

// ---------------- prep: w_reg -> A2pack, MFMA-A-fragment order, bf16 -------------
// A2pack[s(144)][ot(8)][lane(64)][j(8)]: o = ot*32+(l&31); kk = s*16+(l>>5)*8+j;
// tap = s>>4; c = (s&15)*16 + (l>>5)*8 + j; val = w_reg[(o*256+c)*9 + tap]
__global__ void prep_A2(const float* __restrict__ w_reg, short* __restrict__ A2) {
    int gid = blockIdx.x * 256 + threadIdx.x;    // 73728 threads
    int l  = gid & 63;
    int ot = (gid >> 6) & 7;
    int s  = gid >> 9;
    int o  = ot * 32 + (l & 31);
    int tap = s >> 4;
    int cb  = (s & 15) * 16 + (l >> 5) * 8;
    short* dst = A2 + (size_t)gid * 8;
#pragma unroll
    for (int j = 0; j < 8; ++j)
        dst[j] = f2bf(w_reg[(o * 256 + cb + j) * 9 + tap]);
}

// ---------------- prep: w_up -> Bpack for k3 (unchanged layout) ------------------
__global__ void prep_Bpack(const float* __restrict__ w_up, short* __restrict__ Bpack) {
    int gid = blockIdx.x * 256 + threadIdx.x;    // 131072 threads
    int l  = gid & 63;
    int t  = (gid >> 6) & 7;
    int s  = (gid >> 9) & 63;
    int sx = (gid >> 15) & 1;
    int sy = (gid >> 16) & 1;
    int o  = t * 32 + (l & 31);
    short* dst = Bpack + (size_t)gid * 8;
#pragma unroll
    for (int j = 0; j < 8; ++j) {
        int k  = (l >> 5) * 8 + j;
        int kk = s * 16 + k;
        int c  = kk >> 2;
        int tq = kk & 3;
        int ky = (1 - sy) + 2 * (tq >> 1);
        int kx = (1 - sx) + 2 * (tq & 1);
        dst[j] = f2bf(w_up[(c * 256 + o) * 16 + ky * 4 + kx]);
    }
}

// ---------------- k1: offset(18)+mask(9) 3x3 conv, 8-way c-split, XCD-pinned -----
// grid = 1024: b = bx&7 (XCD pin), hg = (bx>>3)&15, s = bx>>7
__global__ __launch_bounds__(256) void k1_offmask(
    const float* __restrict__ x, const float* __restrict__ w_off,
    const float* __restrict__ w_mod, float* __restrict__ part) {
    int bx = blockIdx.x;
    int b  = bx & 7;
    int hg = (bx >> 3) & 15;
    int s  = bx >> 7;
    int row = threadIdx.x >> 6;
    int w   = threadIdx.x & 63;
    int h   = hg * 4 + row;

    float acc[27];
#pragma unroll
    for (int i = 0; i < 27; ++i) acc[i] = 0.f;

    const float* xb = x + (size_t)b * 256 * 4096;
    int c0 = s * 32;
    for (int c = c0; c < c0 + 32; ++c) {
        float xv[9];
#pragma unroll
        for (int dy = 0; dy < 3; ++dy) {
            int yy = h - 1 + dy;
#pragma unroll
            for (int dx = 0; dx < 3; ++dx) {
                int xx = w - 1 + dx;
                bool ok = (yy >= 0) & (yy < 64) & (xx >= 0) & (xx < 64);
                xv[dy * 3 + dx] = ok ? xb[c * 4096 + yy * 64 + xx] : 0.f;
            }
        }
#pragma unroll
        for (int co = 0; co < 27; ++co) {
            const float* wp = (co < 18) ? (w_off + (co * 256 + c) * 9)
                                        : (w_mod + ((co - 18) * 256 + c) * 9);
            float a = acc[co];
#pragma unroll
            for (int t = 0; t < 9; ++t) a = fmaf(xv[t], wp[t], a);
            acc[co] = a;
        }
    }
    size_t base = (size_t)(s * 8 + b) * 27 * 4096 + h * 64 + w;
#pragma unroll
    for (int co = 0; co < 27; ++co) part[base + (size_t)co * 4096] = acc[co];
}

// ---------------- k1b: combine 8 partials + bias (+ 2*sigmoid for mask) ----------
__global__ void k1_combine(const float* __restrict__ part,
                           const float* __restrict__ b_off,
                           const float* __restrict__ b_mod,
                           float* __restrict__ offmask) {
    int e = blockIdx.x * 256 + threadIdx.x;
    int hw = e & 4095;
    int t  = e >> 12;
    int co = t % 27;
    int b  = t / 27;
    float sum = 0.f;
#pragma unroll
    for (int s = 0; s < 8; ++s)
        sum += part[(size_t)((s * 8 + b) * 27 + co) * 4096 + hw];
    if (co < 18) {
        sum += b_off[co];
    } else {
        sum += b_mod[co - 18];
        sum = 2.f / (1.f + expf(-sum));
    }
    offmask[e] = sum;
}

// ---------------- k2: deform sample + MFMA GEMM + bn1 + relu -> h1 (bf16) --------
// Block = (b = bx&7 XCD pin, h = bx>>3): M=256 o, N=64 pos (row h), K=2304
// (kk = tap*256 + c). 4 waves: wave w -> o-tiles {2w, 2w+1}, both pos-tiles.
// Gather: thread (p2=tid&31, og=tid>>5) samples pos {p2,p2+32} x c {cc+4og..+3},
// writes bf16 v to lds_v[pos][c_local] (pitch 40 shorts). A-frags prepacked global.
__global__ __launch_bounds__(256, 2) void k2_deform(
    const float* __restrict__ x, const float* __restrict__ offmask,
    const short* __restrict__ A2,
    const float* __restrict__ g1, const float* __restrict__ be1,
    const float* __restrict__ mu1, const float* __restrict__ va1,
    unsigned short* __restrict__ h1) {
    __shared__ unsigned short lds_v[64 * 40];   // [pos][c_local(32) pad->40]

    int bx = blockIdx.x;
    int b  = bx & 7;
    int h  = bx >> 3;
    int tid = threadIdx.x;
    int p2 = tid & 31;
    int og = tid >> 5;          // 0..7 (gather role)
    int lane = tid & 63;        // MFMA role
    int wv   = tid >> 6;
    int ln = lane & 31;
    int lh = lane >> 5;
    int w2 = wv * 2;            // first o-tile of this wave

    f32x16 acc[2][2];
#pragma unroll
    for (int i = 0; i < 2; ++i)
#pragma unroll
        for (int pt = 0; pt < 2; ++pt)
#pragma unroll
            for (int r = 0; r < 16; ++r) acc[i][pt][r] = 0.f;

    const float* omb = offmask + (size_t)b * 27 * 4096 + h * 64;
    const float* xbb = x + (size_t)b * 256 * 4096;

    for (int k = 0; k < 9; ++k) {
        int ky = k / 3, kx = k - 3 * (k / 3);
        int idxs[2][4];
        float wts[2][4];
#pragma unroll
        for (int pp = 0; pp < 2; ++pp) {
            int pos = p2 + pp * 32;
            float oy = omb[(2 * k) * 4096 + pos];
            float ox = omb[(2 * k + 1) * 4096 + pos];
            float m2 = omb[(18 + k) * 4096 + pos];
            float py = (float)(h - 1 + ky) + oy;
            float px = (float)(pos - 1 + kx) + ox;
            float y0f = floorf(py), x0f = floorf(px);
            float wy1 = py - y0f, wy0 = 1.f - wy1;
            float wx1 = px - x0f, wx0 = 1.f - wx1;
            int y0 = (int)y0f, xq = (int)x0f;
            int y1 = y0 + 1, x1 = xq + 1;
            bool vy0 = (y0 >= 0) & (y0 < 64), vy1 = (y1 >= 0) & (y1 < 64);
            bool vx0 = (xq >= 0) & (xq < 64), vx1 = (x1 >= 0) & (x1 < 64);
            int y0c = min(max(y0, 0), 63), y1c = min(max(y1, 0), 63);
            int x0c = min(max(xq, 0), 63), x1c = min(max(x1, 0), 63);
            idxs[pp][0] = y0c * 64 + x0c;  wts[pp][0] = (vy0 && vx0) ? m2 * wy0 * wx0 : 0.f;
            idxs[pp][1] = y0c * 64 + x1c;  wts[pp][1] = (vy0 && vx1) ? m2 * wy0 * wx1 : 0.f;
            idxs[pp][2] = y1c * 64 + x0c;  wts[pp][2] = (vy1 && vx0) ? m2 * wy1 * wx0 : 0.f;
            idxs[pp][3] = y1c * 64 + x1c;  wts[pp][3] = (vy1 && vx1) ? m2 * wy1 * wx1 : 0.f;
        }

        for (int cc = 0; cc < 256; cc += 32) {
            // ---- gather: 2 pos x 4 c per thread, pack pairs -> LDS bf16 ----
#pragma unroll
            for (int u = 0; u < 2; ++u) {
                int c0 = cc + og * 4 + u * 2;
                const float* xp0 = xbb + (size_t)c0 * 4096;
                const float* xp1 = xp0 + 4096;
#pragma unroll
                for (int pp = 0; pp < 2; ++pp) {
                    float vA = wts[pp][0] * xp0[idxs[pp][0]] + wts[pp][1] * xp0[idxs[pp][1]]
                             + wts[pp][2] * xp0[idxs[pp][2]] + wts[pp][3] * xp0[idxs[pp][3]];
                    float vB = wts[pp][0] * xp1[idxs[pp][0]] + wts[pp][1] * xp1[idxs[pp][1]]
                             + wts[pp][2] * xp1[idxs[pp][2]] + wts[pp][3] * xp1[idxs[pp][3]];
                    ((unsigned*)lds_v)[(p2 + pp * 32) * 20 + og * 2 + u] = pack2bf(vA, vB);
                }
            }
            __syncthreads();

            // ---- MFMA: 2 K-steps of 16 ----
            int base_s = k * 16 + (cc >> 4);
#pragma unroll
            for (int sl = 0; sl < 2; ++sl) {
                int s = base_s + sl;
                short8_t bfr[2];
#pragma unroll
                for (int pt = 0; pt < 2; ++pt)
                    bfr[pt] = *(const short8_t*)&lds_v[(pt * 32 + ln) * 40 + sl * 16 + lh * 8];
#pragma unroll
                for (int i = 0; i < 2; ++i) {
                    const short* ap = A2 + (((size_t)s * 8 + (w2 + i)) * 64 + lane) * 8;
                    short8_t afr = *(const short8_t*)ap;
#pragma unroll
                    for (int pt = 0; pt < 2; ++pt)
                        acc[i][pt] = __builtin_amdgcn_mfma_f32_32x32x16_bf16(
                            afr, bfr[pt], acc[i][pt], 0, 0, 0);
                }
            }
            __syncthreads();
        }
    }

    // ---- epilogue: bn1+relu, store bf16. row=(reg&3)+8*(reg>>2)+4*lh, col=pos ---
#pragma unroll
    for (int i = 0; i < 2; ++i) {
#pragma unroll
        for (int reg = 0; reg < 16; ++reg) {
            int o = (w2 + i) * 32 + (reg & 3) + 8 * (reg >> 2) + 4 * lh;
            float sc = g1[o] / sqrtf(va1[o] + EPSV);
            float sh = be1[o] - mu1[o] * sc;
            size_t ob = ((size_t)(b * 256 + o) * 64 + h) * 64;
#pragma unroll
            for (int pt = 0; pt < 2; ++pt) {
                float v = fmaxf(fmaf(acc[i][pt][reg], sc, sh), 0.f);
                h1[ob + pt * 32 + ln] = (unsigned short)f2bf(v);
            }
        }
    }
}

// ---------------- k3: conv_transpose via bf16 MFMA + bn2 + relu ------------------
// h1 now bf16. Block = (b = bx&7 XCD pin, m = (bx>>3)&63, sy = bx>>9).
__global__ __launch_bounds__(256, 2) void k3_convt(
    const unsigned short* __restrict__ h1, const short* __restrict__ Bpack,
    const float* __restrict__ g2, const float* __restrict__ be2,
    const float* __restrict__ mu2, const float* __restrict__ va2,
    float* __restrict__ out) {
    __shared__ short halo[32 * 2 * 66];   // [c_local][row(top/bot)][col+1], bf16

    int bx = blockIdx.x;
    int b  = bx & 7;
    int m  = (bx >> 3) & 63;
    int sy = bx >> 9;
    int tid  = threadIdx.x;
    int lane = tid & 63;
    int w    = tid >> 6;
    int Mbase = (w & 1) * 32;
    int nb    = (w >> 1) * 4;
    int ln = lane & 31;
    int lh = lane >> 5;

    int i_top = sy ? (m + 1) : m;
    int i_bot = sy ? m : (m - 1);
    bool vtop = (i_top < 64);
    bool vbot = (i_bot >= 0);

    f32x16 acc[2][4];
#pragma unroll
    for (int s = 0; s < 2; ++s)
#pragma unroll
        for (int t = 0; t < 4; ++t)
#pragma unroll
            for (int r = 0; r < 16; ++r) acc[s][t][r] = 0.f;

    const unsigned short* hbase = h1 + (size_t)b * 256 * 4096;

    for (int cc = 0; cc < 256; cc += 32) {
#pragma unroll
        for (int it = 0; it < 16; ++it) {
            int e   = tid + it * 256;
            int c_l = e >> 7;
            int r   = (e >> 6) & 1;
            int col = e & 63;
            int i   = r ? i_bot : i_top;
            bool v  = r ? vbot : vtop;
            unsigned short f = v ? hbase[(size_t)(cc + c_l) * 4096 + i * 64 + col] : 0;
            halo[(c_l * 2 + r) * 66 + col + 1] = (short)f;
        }
        if (tid < 128) {
            int c_l = tid >> 2;
            int r   = (tid >> 1) & 1;
            int end = tid & 1;
            halo[(c_l * 2 + r) * 66 + end * 65] = 0;
        }
        __syncthreads();

#pragma unroll
        for (int s8 = 0; s8 < 8; ++s8) {
            int c0 = s8 * 4;
            short8_t afr[2];
#pragma unroll
            for (int sx = 0; sx < 2; ++sx) {
#pragma unroll
                for (int j = 0; j < 8; ++j) {
                    int c_l = c0 + lh * 2 + (j >> 2);
                    int ty  = (j >> 1) & 1;
                    int tx  = j & 1;
                    afr[sx][j] = halo[(c_l * 2 + ty) * 66 + (Mbase + ln) + sx + 1 - tx];
                }
            }
            int sstep = (cc >> 2) + s8;
#pragma unroll
            for (int sx = 0; sx < 2; ++sx) {
                size_t base = ((((size_t)(sy * 2 + sx) * 64 + sstep) * 8) * 64 + lane) * 8;
#pragma unroll
                for (int tt = 0; tt < 4; ++tt) {
                    short8_t bfr = *(const short8_t*)(Bpack + base + (size_t)(nb + tt) * 512);
                    acc[sx][tt] = __builtin_amdgcn_mfma_f32_32x32x16_bf16(
                        afr[sx], bfr, acc[sx][tt], 0, 0, 0);
                }
            }
        }
        __syncthreads();
    }

    int y = 2 * m + sy;
#pragma unroll
    for (int tt = 0; tt < 4; ++tt) {
        int o = (nb + tt) * 32 + ln;
        float sc = g2[o] / sqrtf(va2[o] + EPSV);
        float sh = be2[o] - mu2[o] * sc;
        size_t ob = ((size_t)(b * 256 + o) * 128 + y) * 128;
#pragma unroll
        for (int sx = 0; sx < 2; ++sx) {
#pragma unroll
            for (int reg = 0; reg < 16; ++reg) {
                int row = (reg & 3) + 8 * (reg >> 2) + 4 * lh;
                int xx = 2 * (Mbase + row) + sx;
                out[ob + xx] = fmaxf(fmaf(acc[sx][tt][reg], sc, sh), 0.f);
            }
        }
    }
}

extern "C" void kernel_launch(void* const* d_in, const int* in_sizes, int n_in,
                              void* d_out, int out_size, void* d_ws, size_t ws_size,
                              hipStream_t stream) {
    const float* x      = (const float*)d_in[0];
    const float* w_off  = (const float*)d_in[1];
    const float* b_off  = (const float*)d_in[2];
    const float* w_mod  = (const float*)d_in[3];
    const float* b_mod  = (const float*)d_in[4];
    const float* w_reg  = (const float*)d_in[5];
    const float* g1     = (const float*)d_in[6];
    const float* be1    = (const float*)d_in[7];
    const float* mu1    = (const float*)d_in[8];
    const float* va1    = (const float*)d_in[9];
    const float* w_up   = (const float*)d_in[10];
    const float* g2     = (const float*)d_in[11];
    const float* be2    = (const float*)d_in[12];
    const float* mu2    = (const float*)d_in[13];
    const float* va2    = (const float*)d_in[14];

    float* ws      = (float*)d_ws;
    float* part    = ws;                        // 7,077,888 floats
    float* offmask = part + 7077888;            //   884,736 floats
    short* A2      = (short*)(offmask + 884736);      //   589,824 shorts (294,912 f)
    short* Bpack   = (short*)(offmask + 884736 + 294912);  // 1,048,576 shorts (524,288 f)
    unsigned short* h1 = (unsigned short*)(offmask + 884736 + 294912 + 524288); // 8,388,608 shorts

    prep_A2   <<<288,  256, 0, stream>>>(w_reg, A2);
    prep_Bpack<<<512,  256, 0, stream>>>(w_up, Bpack);
    k1_offmask<<<1024, 256, 0, stream>>>(x, w_off, w_mod, part);
    k1_combine<<<3456, 256, 0, stream>>>(part, b_off, b_mod, offmask);
    k2_deform <<<512,  256, 0, stream>>>(x, offmask, A2, g1, be1, mu1, va1, h1);
    k3_convt  <<<1024, 256, 0, stream>>>(h1, Bpack, g2, be2, mu2, va2, (float*)d_out);
}

// Round 5
// 574.752 us; speedup vs baseline: 14.7470x; 1.2756x over previous
//
#include <hip/hip_runtime.h>
#include <math.h>

#define EPSV 1e-5f

typedef __attribute__((ext_vector_type(8)))  short short8_t;
typedef __attribute__((ext_vector_type(16))) float f32x16;

static __device__ __forceinline__ short f2bf(float f) {
    union { float f; unsigned u; } v; v.f = f;
    unsigned r = (v.u + 0x7FFFu + ((v.u >> 16) & 1u)) >> 16;
    return (short)r;
}
static __device__ __forceinline__ unsigned pack2bf(float a, float b) {
    return (unsigned)(unsigned short)f2bf(a) | ((unsigned)(unsigned short)f2bf(b) << 16);
}
static __device__ __forceinline__ float bflo(unsigned u) {
    union { unsigned u; float f; } t; t.u = u << 16; return t.f;
}
static __device__ __forceinline__ float bfhi(unsigned u) {
    union { unsigned u; float f; } t; t.u = u & 0xffff0000u; return t.f;
}

// ---------------- prep: w_reg -> A2pack, MFMA-A-fragment order, bf16 -------------
// A2[s(144)][ot(8)][lane(64)][j(8)]: o = ot*32+(l&31); tap = s>>4;
// c = (s&15)*16 + (l>>5)*8 + j; val = w_reg[(o*256+c)*9 + tap]
__global__ void prep_A2(const float* __restrict__ w_reg, short* __restrict__ A2) {
    int gid = blockIdx.x * 256 + threadIdx.x;    // 73728 threads
    int l  = gid & 63;
    int ot = (gid >> 6) & 7;
    int s  = gid >> 9;
    int o  = ot * 32 + (l & 31);
    int tap = s >> 4;
    int cb  = (s & 15) * 16 + (l >> 5) * 8;
    short* dst = A2 + (size_t)gid * 8;
#pragma unroll
    for (int j = 0; j < 8; ++j)
        dst[j] = f2bf(w_reg[(o * 256 + cb + j) * 9 + tap]);
}

// ---------------- prep: w_up -> Bpack for k3 (unchanged layout) ------------------
__global__ void prep_Bpack(const float* __restrict__ w_up, short* __restrict__ Bpack) {
    int gid = blockIdx.x * 256 + threadIdx.x;    // 131072 threads
    int l  = gid & 63;
    int t  = (gid >> 6) & 7;
    int s  = (gid >> 9) & 63;
    int sx = (gid >> 15) & 1;
    int sy = (gid >> 16) & 1;
    int o  = t * 32 + (l & 31);
    short* dst = Bpack + (size_t)gid * 8;
#pragma unroll
    for (int j = 0; j < 8; ++j) {
        int k  = (l >> 5) * 8 + j;
        int kk = s * 16 + k;
        int c  = kk >> 2;
        int tq = kk & 3;
        int ky = (1 - sy) + 2 * (tq >> 1);
        int kx = (1 - sx) + 2 * (tq & 1);
        dst[j] = f2bf(w_up[(c * 256 + o) * 16 + ky * 4 + kx]);
    }
}

// ---------------- k0: x (NCHW fp32) -> xT (NHWC bf16), 64x64 LDS tiles -----------
// grid = 2048: b = bx&7 (XCD pin), hwt = (bx>>3)&63, ct = bx>>9
__global__ __launch_bounds__(256) void k0_nhwc(
    const float* __restrict__ x, unsigned short* __restrict__ xT) {
    __shared__ unsigned short t[64 * 65];
    int bx = blockIdx.x;
    int b   = bx & 7;
    int hwt = (bx >> 3) & 63;
    int ct  = bx >> 9;
    int tid = threadIdx.x;
    int g   = tid >> 6;
    int l   = tid & 63;
    const float* xb = x + ((size_t)b * 256 + ct * 64) * 4096 + hwt * 64;
#pragma unroll
    for (int i = 0; i < 16; ++i) {
        int c_l = g * 16 + i;
        t[c_l * 65 + l] = (unsigned short)f2bf(xb[(size_t)c_l * 4096 + l]);
    }
    __syncthreads();
    unsigned short* xo = xT + ((size_t)b * 4096 + hwt * 64) * 256 + ct * 64;
#pragma unroll
    for (int i = 0; i < 16; ++i) {
        int hw_l = g * 16 + i;
        xo[(size_t)hw_l * 256 + l] = t[l * 65 + hw_l];
    }
}

// ---------------- k1: offset(18)+mask(9) 3x3 conv, 8-way c-split, XCD-pinned -----
__global__ __launch_bounds__(256) void k1_offmask(
    const float* __restrict__ x, const float* __restrict__ w_off,
    const float* __restrict__ w_mod, float* __restrict__ part) {
    int bx = blockIdx.x;
    int b  = bx & 7;
    int hg = (bx >> 3) & 15;
    int s  = bx >> 7;
    int row = threadIdx.x >> 6;
    int w   = threadIdx.x & 63;
    int h   = hg * 4 + row;

    float acc[27];
#pragma unroll
    for (int i = 0; i < 27; ++i) acc[i] = 0.f;

    const float* xb = x + (size_t)b * 256 * 4096;
    int c0 = s * 32;
    for (int c = c0; c < c0 + 32; ++c) {
        float xv[9];
#pragma unroll
        for (int dy = 0; dy < 3; ++dy) {
            int yy = h - 1 + dy;
#pragma unroll
            for (int dx = 0; dx < 3; ++dx) {
                int xx = w - 1 + dx;
                bool ok = (yy >= 0) & (yy < 64) & (xx >= 0) & (xx < 64);
                xv[dy * 3 + dx] = ok ? xb[c * 4096 + yy * 64 + xx] : 0.f;
            }
        }
#pragma unroll
        for (int co = 0; co < 27; ++co) {
            const float* wp = (co < 18) ? (w_off + (co * 256 + c) * 9)
                                        : (w_mod + ((co - 18) * 256 + c) * 9);
            float a = acc[co];
#pragma unroll
            for (int t = 0; t < 9; ++t) a = fmaf(xv[t], wp[t], a);
            acc[co] = a;
        }
    }
    size_t base = (size_t)(s * 8 + b) * 27 * 4096 + h * 64 + w;
#pragma unroll
    for (int co = 0; co < 27; ++co) part[base + (size_t)co * 4096] = acc[co];
}

// ---------------- k2: deform sample (NHWC coalesced) + MFMA + bn1+relu -> h1 -----
// Block = (b = bx&7, h = bx>>3), 512 threads (8 waves). M=256 o, N=64 pos, K=2304.
// Precompute: all 9 taps x 64 pos corner idx/wt from `part` (k1_combine folded in).
// Per tap: wave w gathers pos w*8..w*8+7 (4 coalesced 512B corner loads each),
// then 16 MFMA K-steps (wave w -> o-tile w, 2 pos-tiles).
__global__ __launch_bounds__(512, 4) void k2_deform(
    const unsigned short* __restrict__ xT, const float* __restrict__ part,
    const float* __restrict__ b_off, const float* __restrict__ b_mod,
    const short* __restrict__ A2,
    const float* __restrict__ g1, const float* __restrict__ be1,
    const float* __restrict__ mu1, const float* __restrict__ va1,
    unsigned short* __restrict__ h1) {
    __shared__ unsigned short lds_v[64 * 264];   // [pos][c], pitch 264 (16B-aligned)
    __shared__ int   sidx[9][64][4];
    __shared__ float swt [9][64][4];

    int bx = blockIdx.x;
    int b  = bx & 7;
    int h  = bx >> 3;
    int tid  = threadIdx.x;
    int lane = tid & 63;
    int wv   = tid >> 6;          // 0..7
    int ln = lane & 31;
    int lh = lane >> 5;

    // ---- precompute all (tap,pos) offsets: fold bias + sigmoid (ex k1_combine) --
#pragma unroll
    for (int it = 0; it < 2; ++it) {
        int e = it * 512 + tid;
        if (e < 576) {
            int tap = e >> 6;
            int pos = e & 63;
            float oy = b_off[2 * tap], ox = b_off[2 * tap + 1], mm = b_mod[tap];
            const float* pb = part + (size_t)b * 27 * 4096 + h * 64 + pos;
#pragma unroll
            for (int s = 0; s < 8; ++s) {
                const float* pp = pb + (size_t)s * 8 * 27 * 4096;
                oy += pp[(2 * tap) * 4096];
                ox += pp[(2 * tap + 1) * 4096];
                mm += pp[(18 + tap) * 4096];
            }
            float m2 = 2.f / (1.f + expf(-mm));
            int ky = tap / 3, kx = tap - 3 * (tap / 3);
            float py = (float)(h - 1 + ky) + oy;
            float px = (float)(pos - 1 + kx) + ox;
            float y0f = floorf(py), x0f = floorf(px);
            float wy1 = py - y0f, wy0 = 1.f - wy1;
            float wx1 = px - x0f, wx0 = 1.f - wx1;
            int y0 = (int)y0f, xq = (int)x0f;
            int y1 = y0 + 1, x1 = xq + 1;
            bool vy0 = (y0 >= 0) & (y0 < 64), vy1 = (y1 >= 0) & (y1 < 64);
            bool vx0 = (xq >= 0) & (xq < 64), vx1 = (x1 >= 0) & (x1 < 64);
            int y0c = min(max(y0, 0), 63), y1c = min(max(y1, 0), 63);
            int x0c = min(max(xq, 0), 63), x1c = min(max(x1, 0), 63);
            sidx[tap][pos][0] = y0c * 64 + x0c;  swt[tap][pos][0] = (vy0 && vx0) ? m2 * wy0 * wx0 : 0.f;
            sidx[tap][pos][1] = y0c * 64 + x1c;  swt[tap][pos][1] = (vy0 && vx1) ? m2 * wy0 * wx1 : 0.f;
            sidx[tap][pos][2] = y1c * 64 + x0c;  swt[tap][pos][2] = (vy1 && vx0) ? m2 * wy1 * wx0 : 0.f;
            sidx[tap][pos][3] = y1c * 64 + x1c;  swt[tap][pos][3] = (vy1 && vx1) ? m2 * wy1 * wx1 : 0.f;
        }
    }
    __syncthreads();

    f32x16 acc[2];
#pragma unroll
    for (int pt = 0; pt < 2; ++pt)
#pragma unroll
        for (int r = 0; r < 16; ++r) acc[pt][r] = 0.f;

    const unsigned* xTb = (const unsigned*)(xT + (size_t)b * 4096 * 256);

    for (int k = 0; k < 9; ++k) {
        // ---- gather: wave wv -> 8 pos, coalesced 512B corner rows ----
#pragma unroll
        for (int q = 0; q < 8; ++q) {
            int pos = wv * 8 + q;
            float a0 = 0.f, a1 = 0.f, a2 = 0.f, a3 = 0.f;
#pragma unroll
            for (int i = 0; i < 4; ++i) {
                int   idx = sidx[k][pos][i];
                float wt  = swt[k][pos][i];
                const unsigned* cp = xTb + ((size_t)idx << 7) + (lane << 1);
                unsigned u0 = cp[0], u1 = cp[1];
                a0 = fmaf(wt, bflo(u0), a0);
                a1 = fmaf(wt, bfhi(u0), a1);
                a2 = fmaf(wt, bflo(u1), a2);
                a3 = fmaf(wt, bfhi(u1), a3);
            }
            unsigned* dst = (unsigned*)&lds_v[pos * 264 + lane * 4];
            dst[0] = pack2bf(a0, a1);
            dst[1] = pack2bf(a2, a3);
        }
        __syncthreads();

        // ---- MFMA: 16 K-steps of 16; wave -> o-tile wv, 2 pos-tiles ----
#pragma unroll 4
        for (int sl = 0; sl < 16; ++sl) {
            int s = k * 16 + sl;
            short8_t afr = *(const short8_t*)(A2 + (((size_t)s * 8 + wv) * 64 + lane) * 8);
            short8_t b0 = *(const short8_t*)&lds_v[ln        * 264 + sl * 16 + lh * 8];
            short8_t b1 = *(const short8_t*)&lds_v[(32 + ln) * 264 + sl * 16 + lh * 8];
            acc[0] = __builtin_amdgcn_mfma_f32_32x32x16_bf16(afr, b0, acc[0], 0, 0, 0);
            acc[1] = __builtin_amdgcn_mfma_f32_32x32x16_bf16(afr, b1, acc[1], 0, 0, 0);
        }
        __syncthreads();
    }

    // ---- epilogue: bn1+relu -> h1 bf16. row=(reg&3)+8*(reg>>2)+4*lh, col=pos ----
#pragma unroll
    for (int reg = 0; reg < 16; ++reg) {
        int o = wv * 32 + (reg & 3) + 8 * (reg >> 2) + 4 * lh;
        float sc = g1[o] / sqrtf(va1[o] + EPSV);
        float sh = be1[o] - mu1[o] * sc;
        size_t ob = ((size_t)(b * 256 + o) * 64 + h) * 64;
#pragma unroll
        for (int pt = 0; pt < 2; ++pt) {
            float v = fmaxf(fmaf(acc[pt][reg], sc, sh), 0.f);
            h1[ob + pt * 32 + ln] = (unsigned short)f2bf(v);
        }
    }
}

// ---------------- k3: conv_transpose via bf16 MFMA + bn2 + relu ------------------
__global__ __launch_bounds__(256, 2) void k3_convt(
    const unsigned short* __restrict__ h1, const short* __restrict__ Bpack,
    const float* __restrict__ g2, const float* __restrict__ be2,
    const float* __restrict__ mu2, const float* __restrict__ va2,
    float* __restrict__ out) {
    __shared__ short halo[32 * 2 * 66];

    int bx = blockIdx.x;
    int b  = bx & 7;
    int m  = (bx >> 3) & 63;
    int sy = bx >> 9;
    int tid  = threadIdx.x;
    int lane = tid & 63;
    int w    = tid >> 6;
    int Mbase = (w & 1) * 32;
    int nb    = (w >> 1) * 4;
    int ln = lane & 31;
    int lh = lane >> 5;

    int i_top = sy ? (m + 1) : m;
    int i_bot = sy ? m : (m - 1);
    bool vtop = (i_top < 64);
    bool vbot = (i_bot >= 0);

    f32x16 acc[2][4];
#pragma unroll
    for (int s = 0; s < 2; ++s)
#pragma unroll
        for (int t = 0; t < 4; ++t)
#pragma unroll
            for (int r = 0; r < 16; ++r) acc[s][t][r] = 0.f;

    const unsigned short* hbase = h1 + (size_t)b * 256 * 4096;

    for (int cc = 0; cc < 256; cc += 32) {
#pragma unroll
        for (int it = 0; it < 16; ++it) {
            int e   = tid + it * 256;
            int c_l = e >> 7;
            int r   = (e >> 6) & 1;
            int col = e & 63;
            int i   = r ? i_bot : i_top;
            bool v  = r ? vbot : vtop;
            unsigned short f = v ? hbase[(size_t)(cc + c_l) * 4096 + i * 64 + col] : 0;
            halo[(c_l * 2 + r) * 66 + col + 1] = (short)f;
        }
        if (tid < 128) {
            int c_l = tid >> 2;
            int r   = (tid >> 1) & 1;
            int end = tid & 1;
            halo[(c_l * 2 + r) * 66 + end * 65] = 0;
        }
        __syncthreads();

#pragma unroll
        for (int s8 = 0; s8 < 8; ++s8) {
            int c0 = s8 * 4;
            short8_t afr[2];
#pragma unroll
            for (int sx = 0; sx < 2; ++sx) {
#pragma unroll
                for (int j = 0; j < 8; ++j) {
                    int c_l = c0 + lh * 2 + (j >> 2);
                    int ty  = (j >> 1) & 1;
                    int tx  = j & 1;
                    afr[sx][j] = halo[(c_l * 2 + ty) * 66 + (Mbase + ln) + sx + 1 - tx];
                }
            }
            int sstep = (cc >> 2) + s8;
#pragma unroll
            for (int sx = 0; sx < 2; ++sx) {
                size_t base = ((((size_t)(sy * 2 + sx) * 64 + sstep) * 8) * 64 + lane) * 8;
#pragma unroll
                for (int tt = 0; tt < 4; ++tt) {
                    short8_t bfr = *(const short8_t*)(Bpack + base + (size_t)(nb + tt) * 512);
                    acc[sx][tt] = __builtin_amdgcn_mfma_f32_32x32x16_bf16(
                        afr[sx], bfr, acc[sx][tt], 0, 0, 0);
                }
            }
        }
        __syncthreads();
    }

    int y = 2 * m + sy;
#pragma unroll
    for (int tt = 0; tt < 4; ++tt) {
        int o = (nb + tt) * 32 + ln;
        float sc = g2[o] / sqrtf(va2[o] + EPSV);
        float sh = be2[o] - mu2[o] * sc;
        size_t ob = ((size_t)(b * 256 + o) * 128 + y) * 128;
#pragma unroll
        for (int sx = 0; sx < 2; ++sx) {
#pragma unroll
            for (int reg = 0; reg < 16; ++reg) {
                int row = (reg & 3) + 8 * (reg >> 2) + 4 * lh;
                int xx = 2 * (Mbase + row) + sx;
                out[ob + xx] = fmaxf(fmaf(acc[sx][tt][reg], sc, sh), 0.f);
            }
        }
    }
}

extern "C" void kernel_launch(void* const* d_in, const int* in_sizes, int n_in,
                              void* d_out, int out_size, void* d_ws, size_t ws_size,
                              hipStream_t stream) {
    const float* x      = (const float*)d_in[0];
    const float* w_off  = (const float*)d_in[1];
    const float* b_off  = (const float*)d_in[2];
    const float* w_mod  = (const float*)d_in[3];
    const float* b_mod  = (const float*)d_in[4];
    const float* w_reg  = (const float*)d_in[5];
    const float* g1     = (const float*)d_in[6];
    const float* be1    = (const float*)d_in[7];
    const float* mu1    = (const float*)d_in[8];
    const float* va1    = (const float*)d_in[9];
    const float* w_up   = (const float*)d_in[10];
    const float* g2     = (const float*)d_in[11];
    const float* be2    = (const float*)d_in[12];
    const float* mu2    = (const float*)d_in[13];
    const float* va2    = (const float*)d_in[14];

    float* ws   = (float*)d_ws;
    float* part = ws;                                    // 7,077,888 f
    short* A2   = (short*)(part + 7077888);              //   589,824 sh
    short* Bpack = A2 + 589824;                          // 1,048,576 sh
    unsigned short* h1 = (unsigned short*)(Bpack + 1048576); // 8,388,608 sh
    unsigned short* xT = h1 + 8388608;                   // 8,388,608 sh

    prep_A2   <<<288,  256, 0, stream>>>(w_reg, A2);
    prep_Bpack<<<512,  256, 0, stream>>>(w_up, Bpack);
    k0_nhwc   <<<2048, 256, 0, stream>>>(x, xT);
    k1_offmask<<<1024, 256, 0, stream>>>(x, w_off, w_mod, part);
    k2_deform <<<512,  512, 0, stream>>>(xT, part, b_off, b_mod, A2,
                                         g1, be1, mu1, va1, h1);
    k3_convt  <<<1024, 256, 0, stream>>>(h1, Bpack, g2, be2, mu2, va2, (float*)d_out);
}

// Round 7
// 512.479 us; speedup vs baseline: 16.5390x; 1.1215x over previous
//
#include <hip/hip_runtime.h>
#include <math.h>

#define EPSV 1e-5f

typedef __attribute__((ext_vector_type(8)))  short short8_t;
typedef __attribute__((ext_vector_type(16))) float f32x16;

static __device__ __forceinline__ short f2bf(float f) {
    union { float f; unsigned u; } v; v.f = f;
    unsigned r = (v.u + 0x7FFFu + ((v.u >> 16) & 1u)) >> 16;
    return (short)r;
}
static __device__ __forceinline__ unsigned pack2bf(float a, float b) {
    return (unsigned)(unsigned short)f2bf(a) | ((unsigned)(unsigned short)f2bf(b) << 16);
}
static __device__ __forceinline__ float bflo(unsigned u) {
    union { unsigned u; float f; } t; t.u = u << 16; return t.f;
}
static __device__ __forceinline__ float bfhi(unsigned u) {
    union { unsigned u; float f; } t; t.u = u & 0xffff0000u; return t.f;
}

// ---------------- prep: w_reg -> A2pack (k2 A-fragments), bf16 -------------------
// A2[s(144)][ot(8)][lane(64)][j(8)]: o = ot*32+(l&31); tap = s>>4;
// c = (s&15)*16 + (l>>5)*8 + j; val = w_reg[(o*256+c)*9 + tap]
__global__ void prep_A2(const float* __restrict__ w_reg, short* __restrict__ A2) {
    int gid = blockIdx.x * 256 + threadIdx.x;    // 73728 threads
    int l  = gid & 63;
    int ot = (gid >> 6) & 7;
    int s  = gid >> 9;
    int o  = ot * 32 + (l & 31);
    int tap = s >> 4;
    int cb  = (s & 15) * 16 + (l >> 5) * 8;
    short* dst = A2 + (size_t)gid * 8;
#pragma unroll
    for (int j = 0; j < 8; ++j)
        dst[j] = f2bf(w_reg[(o * 256 + cb + j) * 9 + tap]);
}

// ---------------- prep: w_up -> Aup (k3 A-fragments), bf16 -----------------------
// Aup[sy][sx][s(64)][ot(8)][lane(64)][j(8)]:
//   chunk=s>>4; tap=(s>>2)&3 (ty=tap>>1,tx=tap&1); ch=s&3;
//   o = ot*32+(l&31); c = chunk*64 + ch*16 + (l>>5)*8 + j;
//   ky = (1-sy)+2ty; kx = (1-sx)+2tx; val = w_up[(c*256+o)*16 + ky*4+kx]
// NEEDS 131072 threads (17-bit gid: sy is bit 16) -> grid 512 x 256.
__global__ void prep_Aup(const float* __restrict__ w_up, short* __restrict__ Aup) {
    int gid = blockIdx.x * 256 + threadIdx.x;    // 131072 threads
    int l  = gid & 63;
    int ot = (gid >> 6) & 7;
    int s  = (gid >> 9) & 63;
    int sx = (gid >> 15) & 1;
    int sy = (gid >> 16) & 1;
    int chunk = s >> 4;
    int tap = (s >> 2) & 3;
    int ch  = s & 3;
    int ty = tap >> 1, tx = tap & 1;
    int o  = ot * 32 + (l & 31);
    int cb = chunk * 64 + ch * 16 + (l >> 5) * 8;
    int ky = (1 - sy) + 2 * ty;
    int kx = (1 - sx) + 2 * tx;
    short* dst = Aup + (size_t)gid * 8;
#pragma unroll
    for (int j = 0; j < 8; ++j)
        dst[j] = f2bf(w_up[((cb + j) * 256 + o) * 16 + ky * 4 + kx]);
}

// ---------------- k0: x (NCHW fp32) -> xT (NHWC bf16), 64x64 LDS tiles -----------
__global__ __launch_bounds__(256) void k0_nhwc(
    const float* __restrict__ x, unsigned short* __restrict__ xT) {
    __shared__ unsigned short t[64 * 65];
    int bx = blockIdx.x;
    int b   = bx & 7;
    int hwt = (bx >> 3) & 63;
    int ct  = bx >> 9;
    int tid = threadIdx.x;
    int g   = tid >> 6;
    int l   = tid & 63;
    const float* xb = x + ((size_t)b * 256 + ct * 64) * 4096 + hwt * 64;
#pragma unroll
    for (int i = 0; i < 16; ++i) {
        int c_l = g * 16 + i;
        t[c_l * 65 + l] = (unsigned short)f2bf(xb[(size_t)c_l * 4096 + l]);
    }
    __syncthreads();
    unsigned short* xo = xT + ((size_t)b * 4096 + hwt * 64) * 256 + ct * 64;
#pragma unroll
    for (int i = 0; i < 16; ++i) {
        int hw_l = g * 16 + i;
        xo[(size_t)hw_l * 256 + l] = t[l * 65 + hw_l];
    }
}

// ---------------- k1: offset(18)+mask(9) 3x3 conv, 8-way c-split, XCD-pinned -----
__global__ __launch_bounds__(256) void k1_offmask(
    const float* __restrict__ x, const float* __restrict__ w_off,
    const float* __restrict__ w_mod, float* __restrict__ part) {
    int bx = blockIdx.x;
    int b  = bx & 7;
    int hg = (bx >> 3) & 15;
    int s  = bx >> 7;
    int row = threadIdx.x >> 6;
    int w   = threadIdx.x & 63;
    int h   = hg * 4 + row;

    float acc[27];
#pragma unroll
    for (int i = 0; i < 27; ++i) acc[i] = 0.f;

    const float* xb = x + (size_t)b * 256 * 4096;
    int c0 = s * 32;
    for (int c = c0; c < c0 + 32; ++c) {
        float xv[9];
#pragma unroll
        for (int dy = 0; dy < 3; ++dy) {
            int yy = h - 1 + dy;
#pragma unroll
            for (int dx = 0; dx < 3; ++dx) {
                int xx = w - 1 + dx;
                bool ok = (yy >= 0) & (yy < 64) & (xx >= 0) & (xx < 64);
                xv[dy * 3 + dx] = ok ? xb[c * 4096 + yy * 64 + xx] : 0.f;
            }
        }
#pragma unroll
        for (int co = 0; co < 27; ++co) {
            const float* wp = (co < 18) ? (w_off + (co * 256 + c) * 9)
                                        : (w_mod + ((co - 18) * 256 + c) * 9);
            float a = acc[co];
#pragma unroll
            for (int t = 0; t < 9; ++t) a = fmaf(xv[t], wp[t], a);
            acc[co] = a;
        }
    }
    size_t base = (size_t)(s * 8 + b) * 27 * 4096 + h * 64 + w;
#pragma unroll
    for (int co = 0; co < 27; ++co) part[base + (size_t)co * 4096] = acc[co];
}

// ---------------- k2: deform sample (NHWC coalesced) + MFMA + bn1+relu -> h1 -----
__global__ __launch_bounds__(512, 4) void k2_deform(
    const unsigned short* __restrict__ xT, const float* __restrict__ part,
    const float* __restrict__ b_off, const float* __restrict__ b_mod,
    const short* __restrict__ A2,
    const float* __restrict__ g1, const float* __restrict__ be1,
    const float* __restrict__ mu1, const float* __restrict__ va1,
    unsigned short* __restrict__ h1) {
    __shared__ unsigned short lds_v[64 * 264];   // [pos][c], pitch 264
    __shared__ int   sidx[9][64][4];
    __shared__ float swt [9][64][4];

    int bx = blockIdx.x;
    int b  = bx & 7;
    int h  = bx >> 3;
    int tid  = threadIdx.x;
    int lane = tid & 63;
    int wv   = tid >> 6;          // 0..7
    int ln = lane & 31;
    int lh = lane >> 5;

#pragma unroll
    for (int it = 0; it < 2; ++it) {
        int e = it * 512 + tid;
        if (e < 576) {
            int tap = e >> 6;
            int pos = e & 63;
            float oy = b_off[2 * tap], ox = b_off[2 * tap + 1], mm = b_mod[tap];
            const float* pb = part + (size_t)b * 27 * 4096 + h * 64 + pos;
#pragma unroll
            for (int s = 0; s < 8; ++s) {
                const float* pp = pb + (size_t)s * 8 * 27 * 4096;
                oy += pp[(2 * tap) * 4096];
                ox += pp[(2 * tap + 1) * 4096];
                mm += pp[(18 + tap) * 4096];
            }
            float m2 = 2.f / (1.f + expf(-mm));
            int ky = tap / 3, kx = tap - 3 * (tap / 3);
            float py = (float)(h - 1 + ky) + oy;
            float px = (float)(pos - 1 + kx) + ox;
            float y0f = floorf(py), x0f = floorf(px);
            float wy1 = py - y0f, wy0 = 1.f - wy1;
            float wx1 = px - x0f, wx0 = 1.f - wx1;
            int y0 = (int)y0f, xq = (int)x0f;
            int y1 = y0 + 1, x1 = xq + 1;
            bool vy0 = (y0 >= 0) & (y0 < 64), vy1 = (y1 >= 0) & (y1 < 64);
            bool vx0 = (xq >= 0) & (xq < 64), vx1 = (x1 >= 0) & (x1 < 64);
            int y0c = min(max(y0, 0), 63), y1c = min(max(y1, 0), 63);
            int x0c = min(max(xq, 0), 63), x1c = min(max(x1, 0), 63);
            sidx[tap][pos][0] = y0c * 64 + x0c;  swt[tap][pos][0] = (vy0 && vx0) ? m2 * wy0 * wx0 : 0.f;
            sidx[tap][pos][1] = y0c * 64 + x1c;  swt[tap][pos][1] = (vy0 && vx1) ? m2 * wy0 * wx1 : 0.f;
            sidx[tap][pos][2] = y1c * 64 + x0c;  swt[tap][pos][2] = (vy1 && vx0) ? m2 * wy1 * wx0 : 0.f;
            sidx[tap][pos][3] = y1c * 64 + x1c;  swt[tap][pos][3] = (vy1 && vx1) ? m2 * wy1 * wx1 : 0.f;
        }
    }
    __syncthreads();

    f32x16 acc[2];
#pragma unroll
    for (int pt = 0; pt < 2; ++pt)
#pragma unroll
        for (int r = 0; r < 16; ++r) acc[pt][r] = 0.f;

    const unsigned* xTb = (const unsigned*)(xT + (size_t)b * 4096 * 256);

    for (int k = 0; k < 9; ++k) {
#pragma unroll
        for (int q = 0; q < 8; ++q) {
            int pos = wv * 8 + q;
            float a0 = 0.f, a1 = 0.f, a2 = 0.f, a3 = 0.f;
#pragma unroll
            for (int i = 0; i < 4; ++i) {
                int   idx = sidx[k][pos][i];
                float wt  = swt[k][pos][i];
                const unsigned* cp = xTb + ((size_t)idx << 7) + (lane << 1);
                unsigned u0 = cp[0], u1 = cp[1];
                a0 = fmaf(wt, bflo(u0), a0);
                a1 = fmaf(wt, bfhi(u0), a1);
                a2 = fmaf(wt, bflo(u1), a2);
                a3 = fmaf(wt, bfhi(u1), a3);
            }
            unsigned* dst = (unsigned*)&lds_v[pos * 264 + lane * 4];
            dst[0] = pack2bf(a0, a1);
            dst[1] = pack2bf(a2, a3);
        }
        __syncthreads();

#pragma unroll 4
        for (int sl = 0; sl < 16; ++sl) {
            int s = k * 16 + sl;
            short8_t afr = *(const short8_t*)(A2 + (((size_t)s * 8 + wv) * 64 + lane) * 8);
            short8_t b0 = *(const short8_t*)&lds_v[ln        * 264 + sl * 16 + lh * 8];
            short8_t b1 = *(const short8_t*)&lds_v[(32 + ln) * 264 + sl * 16 + lh * 8];
            acc[0] = __builtin_amdgcn_mfma_f32_32x32x16_bf16(afr, b0, acc[0], 0, 0, 0);
            acc[1] = __builtin_amdgcn_mfma_f32_32x32x16_bf16(afr, b1, acc[1], 0, 0, 0);
        }
        __syncthreads();
    }

#pragma unroll
    for (int reg = 0; reg < 16; ++reg) {
        int o = wv * 32 + (reg & 3) + 8 * (reg >> 2) + 4 * lh;
        float sc = g1[o] / sqrtf(va1[o] + EPSV);
        float sh = be1[o] - mu1[o] * sc;
        size_t ob = ((size_t)(b * 256 + o) * 64 + h) * 64;
#pragma unroll
        for (int pt = 0; pt < 2; ++pt) {
            float v = fmaxf(fmaf(acc[pt][reg], sc, sh), 0.f);
            h1[ob + pt * 32 + ln] = (unsigned short)f2bf(v);
        }
    }
}

// ---------------- k3: conv_transpose via bf16 MFMA, o-on-M + bn2 + relu ----------
// Block = (b = bx&7, y = bx>>3): GEMM M=256 (o), N=128 (x along row y), K=1024
// (4 taps x 256 c). 512 thr / 8 waves: wave (ow = wv&3, sx = wv>>2) handles
// o-tiles {ow, ow+4} x pos-tiles {mh=0,1} of parity sx. A = prepacked Aup
// (global, L2); B staged in LDS [row(2)][col+halo(66)][c-chunk 64, pitch 72].
__global__ __launch_bounds__(512, 2) void k3_convt(
    const unsigned short* __restrict__ h1, const short* __restrict__ Aup,
    const float* __restrict__ g2, const float* __restrict__ be2,
    const float* __restrict__ mu2, const float* __restrict__ va2,
    float* __restrict__ out) {
    __shared__ short lds[2 * 66 * 72];   // 19,008 B

    int bx = blockIdx.x;
    int b  = bx & 7;
    int y  = bx >> 3;            // 0..127
    int sy = y & 1;
    int m  = y >> 1;
    int tid  = threadIdx.x;
    int lane = tid & 63;
    int wv   = tid >> 6;
    int ow = wv & 3;
    int sx = wv >> 2;
    int ln = lane & 31;
    int lh = lane >> 5;

    int row0 = m + sy;           // ty=0 source row
    int row1 = row0 - 1;         // ty=1 source row
    bool v0 = (row0 <= 63);
    bool v1 = (row1 >= 0);

    // zero halo columns (physical col 0 and 65) once; covered by first barrier
    if (tid < 288) {
        int r  = tid / 144;
        int rm = tid - r * 144;
        int cp = (rm / 72) * 65;
        int cc = rm - (rm / 72) * 72;
        lds[(r * 66 + cp) * 72 + cc] = 0;
    }

    f32x16 acc[2][2];            // [o-tile i][mh]
#pragma unroll
    for (int i = 0; i < 2; ++i)
#pragma unroll
        for (int mh = 0; mh < 2; ++mh)
#pragma unroll
            for (int r = 0; r < 16; ++r) acc[i][mh][r] = 0.f;

    const unsigned short* hb = h1 + (size_t)b * 256 * 4096;
    const short* Abase = Aup + (size_t)(sy * 2 + sx) * 64 * 8 * 64 * 8;
    int col = tid & 63;

    for (int cc = 0; cc < 256; cc += 64) {
        // ---- stage: 2 rows x 64 cols x 64 c -> LDS [r][col+1][c] ----
#pragma unroll
        for (int it = 0; it < 4; ++it) {
            int quad = ((tid >> 6) & 7) + (it & 1) * 8;   // 0..15
            int r    = it >> 1;
            int row  = r ? row1 : row0;
            bool v   = r ? v1 : v0;
            int cb   = cc + quad * 4;
            unsigned short u0 = v ? hb[(size_t)(cb + 0) * 4096 + row * 64 + col] : 0;
            unsigned short u1 = v ? hb[(size_t)(cb + 1) * 4096 + row * 64 + col] : 0;
            unsigned short u2 = v ? hb[(size_t)(cb + 2) * 4096 + row * 64 + col] : 0;
            unsigned short u3 = v ? hb[(size_t)(cb + 3) * 4096 + row * 64 + col] : 0;
            unsigned* dst = (unsigned*)&lds[(r * 66 + col + 1) * 72 + quad * 4];
            dst[0] = (unsigned)u0 | ((unsigned)u1 << 16);
            dst[1] = (unsigned)u2 | ((unsigned)u3 << 16);
        }
        __syncthreads();

        // ---- MFMA: 16 K-steps of 16 (tap-major: step = tap*4 + ch) ----
#pragma unroll
        for (int st = 0; st < 16; ++st) {
            int tap = st >> 2;
            int ch  = st & 3;
            int ty = tap >> 1, tx = tap & 1;
            int s_g = (cc >> 2) + st;
            const short* ap = Abase + (((size_t)s_g * 8) * 64 + lane) * 8;
            short8_t a0 = *(const short8_t*)(ap + (size_t)ow * 512);
            short8_t a1 = *(const short8_t*)(ap + (size_t)(ow + 4) * 512);
            int cbase = ty * 66 + ln + sx - tx + 1;
            short8_t b0 = *(const short8_t*)&lds[cbase * 72 + ch * 16 + lh * 8];
            short8_t b1 = *(const short8_t*)&lds[(cbase + 32) * 72 + ch * 16 + lh * 8];
            acc[0][0] = __builtin_amdgcn_mfma_f32_32x32x16_bf16(a0, b0, acc[0][0], 0, 0, 0);
            acc[0][1] = __builtin_amdgcn_mfma_f32_32x32x16_bf16(a0, b1, acc[0][1], 0, 0, 0);
            acc[1][0] = __builtin_amdgcn_mfma_f32_32x32x16_bf16(a1, b0, acc[1][0], 0, 0, 0);
            acc[1][1] = __builtin_amdgcn_mfma_f32_32x32x16_bf16(a1, b1, acc[1][1], 0, 0, 0);
        }
        __syncthreads();
    }

    // ---- epilogue: bn2 + relu -> out fp32 ----
#pragma unroll
    for (int i = 0; i < 2; ++i) {
#pragma unroll
        for (int reg = 0; reg < 16; ++reg) {
            int o = (ow + 4 * i) * 32 + (reg & 3) + 8 * (reg >> 2) + 4 * lh;
            float sc = g2[o] / sqrtf(va2[o] + EPSV);
            float sh = be2[o] - mu2[o] * sc;
            size_t ob = ((size_t)(b * 256 + o) * 128 + y) * 128;
#pragma unroll
            for (int mh = 0; mh < 2; ++mh) {
                int x = 2 * (mh * 32 + ln) + sx;
                out[ob + x] = fmaxf(fmaf(acc[i][mh][reg], sc, sh), 0.f);
            }
        }
    }
}

extern "C" void kernel_launch(void* const* d_in, const int* in_sizes, int n_in,
                              void* d_out, int out_size, void* d_ws, size_t ws_size,
                              hipStream_t stream) {
    const float* x      = (const float*)d_in[0];
    const float* w_off  = (const float*)d_in[1];
    const float* b_off  = (const float*)d_in[2];
    const float* w_mod  = (const float*)d_in[3];
    const float* b_mod  = (const float*)d_in[4];
    const float* w_reg  = (const float*)d_in[5];
    const float* g1     = (const float*)d_in[6];
    const float* be1    = (const float*)d_in[7];
    const float* mu1    = (const float*)d_in[8];
    const float* va1    = (const float*)d_in[9];
    const float* w_up   = (const float*)d_in[10];
    const float* g2     = (const float*)d_in[11];
    const float* be2    = (const float*)d_in[12];
    const float* mu2    = (const float*)d_in[13];
    const float* va2    = (const float*)d_in[14];

    float* ws   = (float*)d_ws;
    float* part = ws;                                        // 7,077,888 f
    short* A2   = (short*)(part + 7077888);                  //   589,824 sh
    short* Aup  = A2 + 589824;                               // 2,097,152 sh (1M used)
    unsigned short* h1 = (unsigned short*)(Aup + 2097152);   // 8,388,608 sh
    unsigned short* xT = h1 + 8388608;                       // 8,388,608 sh

    prep_A2   <<<288,  256, 0, stream>>>(w_reg, A2);
    prep_Aup  <<<512,  256, 0, stream>>>(w_up, Aup);         // FIX: 512 blocks (was 256)
    k0_nhwc   <<<2048, 256, 0, stream>>>(x, xT);
    k1_offmask<<<1024, 256, 0, stream>>>(x, w_off, w_mod, part);
    k2_deform <<<512,  512, 0, stream>>>(xT, part, b_off, b_mod, A2,
                                         g1, be1, mu1, va1, h1);
    k3_convt  <<<1024, 512, 0, stream>>>(h1, Aup, g2, be2, mu2, va2, (float*)d_out);
}

// Round 8
// 380.611 us; speedup vs baseline: 22.2691x; 1.3465x over previous
//
#include <hip/hip_runtime.h>
#include <math.h>

#define EPSV 1e-5f

typedef __attribute__((ext_vector_type(8)))  short short8_t;
typedef __attribute__((ext_vector_type(16))) float f32x16;

static __device__ __forceinline__ short f2bf(float f) {
    union { float f; unsigned u; } v; v.f = f;
    unsigned r = (v.u + 0x7FFFu + ((v.u >> 16) & 1u)) >> 16;
    return (short)r;
}
static __device__ __forceinline__ unsigned pack2bf(float a, float b) {
    return (unsigned)(unsigned short)f2bf(a) | ((unsigned)(unsigned short)f2bf(b) << 16);
}
static __device__ __forceinline__ float bflo(unsigned u) {
    union { unsigned u; float f; } t; t.u = u << 16; return t.f;
}
static __device__ __forceinline__ float bfhi(unsigned u) {
    union { unsigned u; float f; } t; t.u = u & 0xffff0000u; return t.f;
}

// ---------------- prep: w_reg -> A2pack (k2 A-fragments), bf16 -------------------
__global__ void prep_A2(const float* __restrict__ w_reg, short* __restrict__ A2) {
    int gid = blockIdx.x * 256 + threadIdx.x;    // 73728 threads
    int l  = gid & 63;
    int ot = (gid >> 6) & 7;
    int s  = gid >> 9;
    int o  = ot * 32 + (l & 31);
    int tap = s >> 4;
    int cb  = (s & 15) * 16 + (l >> 5) * 8;
    short* dst = A2 + (size_t)gid * 8;
#pragma unroll
    for (int j = 0; j < 8; ++j)
        dst[j] = f2bf(w_reg[(o * 256 + cb + j) * 9 + tap]);
}

// ---------------- prep: w_off/w_mod -> A1 (k1 A-fragments), bf16 -----------------
// A1[s(144)][lane(64)][j(8)]: s = tap*16 + cq; co = l&31 (27 used, pad=0);
// c = cq*16 + (l>>5)*8 + j; val = co<18 ? w_off[(co*256+c)*9+tap]
//                                : co<27 ? w_mod[((co-18)*256+c)*9+tap] : 0
__global__ void prep_A1(const float* __restrict__ w_off,
                        const float* __restrict__ w_mod, short* __restrict__ A1) {
    int gid = blockIdx.x * 256 + threadIdx.x;    // 9216 threads
    int l  = gid & 63;
    int s  = gid >> 6;          // 0..143
    int tap = s >> 4;
    int cq  = s & 15;
    int co  = l & 31;
    int cb  = cq * 16 + (l >> 5) * 8;
    short* dst = A1 + (size_t)gid * 8;
#pragma unroll
    for (int j = 0; j < 8; ++j) {
        int c = cb + j;
        float v = 0.f;
        if (co < 18)      v = w_off[(co * 256 + c) * 9 + tap];
        else if (co < 27) v = w_mod[((co - 18) * 256 + c) * 9 + tap];
        dst[j] = f2bf(v);
    }
}

// ---------------- prep: w_up -> Aup (k3 A-fragments), bf16 -----------------------
__global__ void prep_Aup(const float* __restrict__ w_up, short* __restrict__ Aup) {
    int gid = blockIdx.x * 256 + threadIdx.x;    // 131072 threads
    int l  = gid & 63;
    int ot = (gid >> 6) & 7;
    int s  = (gid >> 9) & 63;
    int sx = (gid >> 15) & 1;
    int sy = (gid >> 16) & 1;
    int chunk = s >> 4;
    int tap = (s >> 2) & 3;
    int ch  = s & 3;
    int ty = tap >> 1, tx = tap & 1;
    int o  = ot * 32 + (l & 31);
    int cb = chunk * 64 + ch * 16 + (l >> 5) * 8;
    int ky = (1 - sy) + 2 * ty;
    int kx = (1 - sx) + 2 * tx;
    short* dst = Aup + (size_t)gid * 8;
#pragma unroll
    for (int j = 0; j < 8; ++j)
        dst[j] = f2bf(w_up[((cb + j) * 256 + o) * 16 + ky * 4 + kx]);
}

// ---------------- k0: x (NCHW fp32) -> xT (NHWC bf16), 64x64 LDS tiles -----------
__global__ __launch_bounds__(256) void k0_nhwc(
    const float* __restrict__ x, unsigned short* __restrict__ xT) {
    __shared__ unsigned short t[64 * 65];
    int bx = blockIdx.x;
    int b   = bx & 7;
    int hwt = (bx >> 3) & 63;
    int ct  = bx >> 9;
    int tid = threadIdx.x;
    int g   = tid >> 6;
    int l   = tid & 63;
    const float* xb = x + ((size_t)b * 256 + ct * 64) * 4096 + hwt * 64;
#pragma unroll
    for (int i = 0; i < 16; ++i) {
        int c_l = g * 16 + i;
        t[c_l * 65 + l] = (unsigned short)f2bf(xb[(size_t)c_l * 4096 + l]);
    }
    __syncthreads();
    unsigned short* xo = xT + ((size_t)b * 4096 + hwt * 64) * 256 + ct * 64;
#pragma unroll
    for (int i = 0; i < 16; ++i) {
        int hw_l = g * 16 + i;
        xo[(size_t)hw_l * 256 + l] = t[l * 65 + hw_l];
    }
}

// ---------------- k1: offset+mask conv via bf16 MFMA -> offmask ------------------
// Block = (b = bx&7, h = bx>>3), 256 thr / 4 waves. GEMM M=32 (27 co), N=64 pos,
// K=2304. LDS: 3 src rows x (64+2 halo) cols x 64-c chunk, pitch 72. Waves
// K-split (16 c each per chunk); cross-wave reduce in LDS; epilogue folds
// bias + 2*sigmoid(mask) -> offmask[b][27][h][pos].
__global__ __launch_bounds__(256, 2) void k1_mfma(
    const unsigned short* __restrict__ xT, const short* __restrict__ A1,
    const float* __restrict__ b_off, const float* __restrict__ b_mod,
    float* __restrict__ offmask) {
    __shared__ short xs[3 * 66 * 72];     // 28,512 B
    __shared__ float red[4][32][64];      // 32,768 B

    int bx = blockIdx.x;
    int b  = bx & 7;
    int h  = bx >> 3;
    int tid  = threadIdx.x;
    int lane = tid & 63;
    int wv   = tid >> 6;       // 0..3 (K-split)
    int ln = lane & 31;
    int lh = lane >> 5;

    // zero halo columns (phys col 0 and 65), all 3 rows, 64 c (32 dwords each)
    if (tid < 192) {
        int r    = tid >> 6;
        int rest = tid & 63;
        int colp = (rest >> 5) * 65;
        int cd   = rest & 31;
        ((unsigned*)xs)[((r * 66 + colp) * 72 >> 1) + cd] = 0;
    }

    f32x16 acc[2];
#pragma unroll
    for (int pt = 0; pt < 2; ++pt)
#pragma unroll
        for (int r = 0; r < 16; ++r) acc[pt][r] = 0.f;

    const unsigned short* xTb = xT + (size_t)b * 4096 * 256;

    for (int cc = 0; cc < 256; cc += 64) {
        // stage 3 rows x 64 cols x 64 c: 1536 short8 units, 6 per thread
#pragma unroll
        for (int it = 0; it < 6; ++it) {
            int e   = tid + it * 256;
            int ch8 = e & 7;             // 8-c chunk
            int col = (e >> 3) & 63;
            int r   = e >> 9;            // 0..2
            int row = h - 1 + r;
            bool v  = (row >= 0) & (row <= 63);
            short8_t val = {0,0,0,0,0,0,0,0};
            if (v) val = *(const short8_t*)(xTb + ((size_t)row * 64 + col) * 256 + cc + ch8 * 8);
            *(short8_t*)&xs[(r * 66 + col + 1) * 72 + ch8 * 8] = val;
        }
        __syncthreads();

#pragma unroll
        for (int tap = 0; tap < 9; ++tap) {
            int ky = tap / 3, kx = tap - 3 * (tap / 3);
            int s = tap * 16 + (cc >> 4) + wv;
            short8_t afr = *(const short8_t*)(A1 + ((size_t)s * 64 + lane) * 8);
            const short* bp = &xs[(ky * 66 + ln + kx) * 72 + wv * 16 + lh * 8];
            short8_t b0 = *(const short8_t*)bp;
            short8_t b1 = *(const short8_t*)(bp + 32 * 72);
            acc[0] = __builtin_amdgcn_mfma_f32_32x32x16_bf16(afr, b0, acc[0], 0, 0, 0);
            acc[1] = __builtin_amdgcn_mfma_f32_32x32x16_bf16(afr, b1, acc[1], 0, 0, 0);
        }
        __syncthreads();
    }

    // cross-wave reduce: row=(reg&3)+8*(reg>>2)+4*lh (co), col=ln
#pragma unroll
    for (int pt = 0; pt < 2; ++pt)
#pragma unroll
        for (int reg = 0; reg < 16; ++reg) {
            int row = (reg & 3) + 8 * (reg >> 2) + 4 * lh;
            red[wv][row][pt * 32 + ln] = acc[pt][reg];
        }
    __syncthreads();

    int pos = tid & 63;
    int cg  = tid >> 6;
#pragma unroll
    for (int i = 0; i < 7; ++i) {
        int co = 4 * i + cg;
        if (co < 27) {
            float sum = red[0][co][pos] + red[1][co][pos]
                      + red[2][co][pos] + red[3][co][pos];
            if (co < 18) {
                sum += b_off[co];
            } else {
                sum += b_mod[co - 18];
                sum = 2.f / (1.f + expf(-sum));
            }
            offmask[((size_t)(b * 27 + co) << 12) + (h << 6) + pos] = sum;
        }
    }
}

// ---------------- k2: deform sample (NHWC coalesced) + MFMA + bn1+relu -> h1 -----
__global__ __launch_bounds__(512, 4) void k2_deform(
    const unsigned short* __restrict__ xT, const float* __restrict__ offmask,
    const short* __restrict__ A2,
    const float* __restrict__ g1, const float* __restrict__ be1,
    const float* __restrict__ mu1, const float* __restrict__ va1,
    unsigned short* __restrict__ h1) {
    __shared__ unsigned short lds_v[64 * 264];   // [pos][c], pitch 264
    __shared__ int   sidx[9][64][4];
    __shared__ float swt [9][64][4];

    int bx = blockIdx.x;
    int b  = bx & 7;
    int h  = bx >> 3;
    int tid  = threadIdx.x;
    int lane = tid & 63;
    int wv   = tid >> 6;          // 0..7
    int ln = lane & 31;
    int lh = lane >> 5;

#pragma unroll
    for (int it = 0; it < 2; ++it) {
        int e = it * 512 + tid;
        if (e < 576) {
            int tap = e >> 6;
            int pos = e & 63;
            const float* om = offmask + ((size_t)b * 27 << 12) + (h << 6) + pos;
            float oy = om[(size_t)(2 * tap) << 12];
            float ox = om[(size_t)(2 * tap + 1) << 12];
            float m2 = om[(size_t)(18 + tap) << 12];
            int ky = tap / 3, kx = tap - 3 * (tap / 3);
            float py = (float)(h - 1 + ky) + oy;
            float px = (float)(pos - 1 + kx) + ox;
            float y0f = floorf(py), x0f = floorf(px);
            float wy1 = py - y0f, wy0 = 1.f - wy1;
            float wx1 = px - x0f, wx0 = 1.f - wx1;
            int y0 = (int)y0f, xq = (int)x0f;
            int y1 = y0 + 1, x1 = xq + 1;
            bool vy0 = (y0 >= 0) & (y0 < 64), vy1 = (y1 >= 0) & (y1 < 64);
            bool vx0 = (xq >= 0) & (xq < 64), vx1 = (x1 >= 0) & (x1 < 64);
            int y0c = min(max(y0, 0), 63), y1c = min(max(y1, 0), 63);
            int x0c = min(max(xq, 0), 63), x1c = min(max(x1, 0), 63);
            sidx[tap][pos][0] = y0c * 64 + x0c;  swt[tap][pos][0] = (vy0 && vx0) ? m2 * wy0 * wx0 : 0.f;
            sidx[tap][pos][1] = y0c * 64 + x1c;  swt[tap][pos][1] = (vy0 && vx1) ? m2 * wy0 * wx1 : 0.f;
            sidx[tap][pos][2] = y1c * 64 + x0c;  swt[tap][pos][2] = (vy1 && vx0) ? m2 * wy1 * wx0 : 0.f;
            sidx[tap][pos][3] = y1c * 64 + x1c;  swt[tap][pos][3] = (vy1 && vx1) ? m2 * wy1 * wx1 : 0.f;
        }
    }
    __syncthreads();

    f32x16 acc[2];
#pragma unroll
    for (int pt = 0; pt < 2; ++pt)
#pragma unroll
        for (int r = 0; r < 16; ++r) acc[pt][r] = 0.f;

    const unsigned* xTb = (const unsigned*)(xT + (size_t)b * 4096 * 256);

    for (int k = 0; k < 9; ++k) {
#pragma unroll
        for (int q = 0; q < 8; ++q) {
            int pos = wv * 8 + q;
            float a0 = 0.f, a1 = 0.f, a2 = 0.f, a3 = 0.f;
#pragma unroll
            for (int i = 0; i < 4; ++i) {
                int   idx = sidx[k][pos][i];
                float wt  = swt[k][pos][i];
                const unsigned* cp = xTb + ((size_t)idx << 7) + (lane << 1);
                unsigned u0 = cp[0], u1 = cp[1];
                a0 = fmaf(wt, bflo(u0), a0);
                a1 = fmaf(wt, bfhi(u0), a1);
                a2 = fmaf(wt, bflo(u1), a2);
                a3 = fmaf(wt, bfhi(u1), a3);
            }
            unsigned* dst = (unsigned*)&lds_v[pos * 264 + lane * 4];
            dst[0] = pack2bf(a0, a1);
            dst[1] = pack2bf(a2, a3);
        }
        __syncthreads();

#pragma unroll 4
        for (int sl = 0; sl < 16; ++sl) {
            int s = k * 16 + sl;
            short8_t afr = *(const short8_t*)(A2 + (((size_t)s * 8 + wv) * 64 + lane) * 8);
            short8_t b0 = *(const short8_t*)&lds_v[ln        * 264 + sl * 16 + lh * 8];
            short8_t b1 = *(const short8_t*)&lds_v[(32 + ln) * 264 + sl * 16 + lh * 8];
            acc[0] = __builtin_amdgcn_mfma_f32_32x32x16_bf16(afr, b0, acc[0], 0, 0, 0);
            acc[1] = __builtin_amdgcn_mfma_f32_32x32x16_bf16(afr, b1, acc[1], 0, 0, 0);
        }
        __syncthreads();
    }

#pragma unroll
    for (int reg = 0; reg < 16; ++reg) {
        int o = wv * 32 + (reg & 3) + 8 * (reg >> 2) + 4 * lh;
        float sc = g1[o] / sqrtf(va1[o] + EPSV);
        float sh = be1[o] - mu1[o] * sc;
        size_t ob = ((size_t)(b * 256 + o) * 64 + h) * 64;
#pragma unroll
        for (int pt = 0; pt < 2; ++pt) {
            float v = fmaxf(fmaf(acc[pt][reg], sc, sh), 0.f);
            h1[ob + pt * 32 + ln] = (unsigned short)f2bf(v);
        }
    }
}

// ---------------- k3: conv_transpose via bf16 MFMA, o-on-M + bn2 + relu ----------
__global__ __launch_bounds__(512, 2) void k3_convt(
    const unsigned short* __restrict__ h1, const short* __restrict__ Aup,
    const float* __restrict__ g2, const float* __restrict__ be2,
    const float* __restrict__ mu2, const float* __restrict__ va2,
    float* __restrict__ out) {
    __shared__ short lds[2 * 66 * 72];   // 19,008 B

    int bx = blockIdx.x;
    int b  = bx & 7;
    int y  = bx >> 3;            // 0..127
    int sy = y & 1;
    int m  = y >> 1;
    int tid  = threadIdx.x;
    int lane = tid & 63;
    int wv   = tid >> 6;
    int ow = wv & 3;
    int sx = wv >> 2;
    int ln = lane & 31;
    int lh = lane >> 5;

    int row0 = m + sy;           // ty=0 source row
    int row1 = row0 - 1;         // ty=1 source row
    bool v0 = (row0 <= 63);
    bool v1 = (row1 >= 0);

    if (tid < 288) {
        int r  = tid / 144;
        int rm = tid - r * 144;
        int cp = (rm / 72) * 65;
        int cc = rm - (rm / 72) * 72;
        lds[(r * 66 + cp) * 72 + cc] = 0;
    }

    f32x16 acc[2][2];            // [o-tile i][mh]
#pragma unroll
    for (int i = 0; i < 2; ++i)
#pragma unroll
        for (int mh = 0; mh < 2; ++mh)
#pragma unroll
            for (int r = 0; r < 16; ++r) acc[i][mh][r] = 0.f;

    const unsigned short* hb = h1 + (size_t)b * 256 * 4096;
    const short* Abase = Aup + (size_t)(sy * 2 + sx) * 64 * 8 * 64 * 8;
    int col = tid & 63;

    for (int cc = 0; cc < 256; cc += 64) {
#pragma unroll
        for (int it = 0; it < 4; ++it) {
            int quad = ((tid >> 6) & 7) + (it & 1) * 8;   // 0..15
            int r    = it >> 1;
            int row  = r ? row1 : row0;
            bool v   = r ? v1 : v0;
            int cb   = cc + quad * 4;
            unsigned short u0 = v ? hb[(size_t)(cb + 0) * 4096 + row * 64 + col] : 0;
            unsigned short u1 = v ? hb[(size_t)(cb + 1) * 4096 + row * 64 + col] : 0;
            unsigned short u2 = v ? hb[(size_t)(cb + 2) * 4096 + row * 64 + col] : 0;
            unsigned short u3 = v ? hb[(size_t)(cb + 3) * 4096 + row * 64 + col] : 0;
            unsigned* dst = (unsigned*)&lds[(r * 66 + col + 1) * 72 + quad * 4];
            dst[0] = (unsigned)u0 | ((unsigned)u1 << 16);
            dst[1] = (unsigned)u2 | ((unsigned)u3 << 16);
        }
        __syncthreads();

#pragma unroll
        for (int st = 0; st < 16; ++st) {
            int tap = st >> 2;
            int ch  = st & 3;
            int ty = tap >> 1, tx = tap & 1;
            int s_g = (cc >> 2) + st;
            const short* ap = Abase + (((size_t)s_g * 8) * 64 + lane) * 8;
            short8_t a0 = *(const short8_t*)(ap + (size_t)ow * 512);
            short8_t a1 = *(const short8_t*)(ap + (size_t)(ow + 4) * 512);
            int cbase = ty * 66 + ln + sx - tx + 1;
            short8_t b0 = *(const short8_t*)&lds[cbase * 72 + ch * 16 + lh * 8];
            short8_t b1 = *(const short8_t*)&lds[(cbase + 32) * 72 + ch * 16 + lh * 8];
            acc[0][0] = __builtin_amdgcn_mfma_f32_32x32x16_bf16(a0, b0, acc[0][0], 0, 0, 0);
            acc[0][1] = __builtin_amdgcn_mfma_f32_32x32x16_bf16(a0, b1, acc[0][1], 0, 0, 0);
            acc[1][0] = __builtin_amdgcn_mfma_f32_32x32x16_bf16(a1, b0, acc[1][0], 0, 0, 0);
            acc[1][1] = __builtin_amdgcn_mfma_f32_32x32x16_bf16(a1, b1, acc[1][1], 0, 0, 0);
        }
        __syncthreads();
    }

#pragma unroll
    for (int i = 0; i < 2; ++i) {
#pragma unroll
        for (int reg = 0; reg < 16; ++reg) {
            int o = (ow + 4 * i) * 32 + (reg & 3) + 8 * (reg >> 2) + 4 * lh;
            float sc = g2[o] / sqrtf(va2[o] + EPSV);
            float sh = be2[o] - mu2[o] * sc;
            size_t ob = ((size_t)(b * 256 + o) * 128 + y) * 128;
#pragma unroll
            for (int mh = 0; mh < 2; ++mh) {
                int x = 2 * (mh * 32 + ln) + sx;
                out[ob + x] = fmaxf(fmaf(acc[i][mh][reg], sc, sh), 0.f);
            }
        }
    }
}

extern "C" void kernel_launch(void* const* d_in, const int* in_sizes, int n_in,
                              void* d_out, int out_size, void* d_ws, size_t ws_size,
                              hipStream_t stream) {
    const float* x      = (const float*)d_in[0];
    const float* w_off  = (const float*)d_in[1];
    const float* b_off  = (const float*)d_in[2];
    const float* w_mod  = (const float*)d_in[3];
    const float* b_mod  = (const float*)d_in[4];
    const float* w_reg  = (const float*)d_in[5];
    const float* g1     = (const float*)d_in[6];
    const float* be1    = (const float*)d_in[7];
    const float* mu1    = (const float*)d_in[8];
    const float* va1    = (const float*)d_in[9];
    const float* w_up   = (const float*)d_in[10];
    const float* g2     = (const float*)d_in[11];
    const float* be2    = (const float*)d_in[12];
    const float* mu2    = (const float*)d_in[13];
    const float* va2    = (const float*)d_in[14];

    float* ws      = (float*)d_ws;
    float* offmask = ws;                                     //   884,736 f
    short* A2      = (short*)(offmask + 884736);             //   589,824 sh
    short* A1      = A2 + 589824;                            //    73,728 sh
    short* Aup     = A1 + 73728;                             // 1,048,576 sh
    unsigned short* h1 = (unsigned short*)(Aup + 1048576);   // 8,388,608 sh
    unsigned short* xT = h1 + 8388608;                       // 8,388,608 sh

    prep_A2   <<<288,  256, 0, stream>>>(w_reg, A2);
    prep_A1   <<<36,   256, 0, stream>>>(w_off, w_mod, A1);
    prep_Aup  <<<512,  256, 0, stream>>>(w_up, Aup);
    k0_nhwc   <<<2048, 256, 0, stream>>>(x, xT);
    k1_mfma   <<<512,  256, 0, stream>>>(xT, A1, b_off, b_mod, offmask);
    k2_deform <<<512,  512, 0, stream>>>(xT, offmask, A2, g1, be1, mu1, va1, h1);
    k3_convt  <<<1024, 512, 0, stream>>>(h1, Aup, g2, be2, mu2, va2, (float*)d_out);
}